// Round 10
// baseline (118.469 us; speedup 1.0000x reference)
//
#include <hip/hip_runtime.h>
#include <hip/hip_bf16.h>
#include <math.h>

#define MM 8192
#define CC 4096
#define DD 768
#define EPSF 1e-8f

#define BM 256
#define BN 256
#define TPB 512
#define NROWT (MM / BM)        // 32
#define NCOLT (CC / BN)        // 16

// ---- ws layout ----
#define XB_OFF 0
#define YB_OFF (MM * DD * 2)
#define FW_OFF (YB_OFF + CC * DD * 2)
#define S_T 0
#define T_T (MM)
#define S_L (2 * MM)
#define T_L (2 * MM + CC)
#define CA_T (2 * MM + 2 * CC)         // t_t / s_t per text row
#define POS  (CA_T + MM)
#define PART (POS + MM)                // MM * NCOLT * 2 floats (top-2 largest u)

typedef __attribute__((ext_vector_type(8))) short short8;
typedef __attribute__((ext_vector_type(4))) unsigned short u16x4;
typedef __attribute__((ext_vector_type(16))) float f32x16;

__device__ inline unsigned short f2bf(float f) {
    unsigned int u = __float_as_uint(f);
    u += 0x7FFF + ((u >> 16) & 1);   // RNE
    return (unsigned short)(u >> 16);
}

__device__ inline void gll16(const void* g, void* l) {
    __builtin_amdgcn_global_load_lds(
        (const __attribute__((address_space(1))) void*)(uintptr_t)g,
        (__attribute__((address_space(3))) void*)(unsigned)(uintptr_t)l,
        16, 0, 0);
}

#define BAR() do { __builtin_amdgcn_sched_barrier(0); __builtin_amdgcn_s_barrier(); __builtin_amdgcn_sched_barrier(0); } while (0)
#define VM8 asm volatile("s_waitcnt vmcnt(8)" ::: "memory")
#define VM4 asm volatile("s_waitcnt vmcnt(4)" ::: "memory")
#define VM0 asm volatile("s_waitcnt vmcnt(0)" ::: "memory")
#define NOPS ((void)0)

#define DSR(dst, base, off) \
    asm volatile("ds_read_b128 %0, %1 offset:%c2" : "=v"(dst) : "v"(base), "n"(off))

#define MFMA32(a, b, c) __builtin_amdgcn_mfma_f32_32x32x16_bf16((a), (b), (c), 0, 0, 0)

// ---------------- prep+convert: per-row s,t,ca + bf16 copies ----------------
__global__ void prep_conv_kernel(const float* __restrict__ X, const float* __restrict__ Y,
                                 const float* curv_log, const float* ta_log, const float* la_log,
                                 char* __restrict__ wsb) {
    unsigned short* Xb = (unsigned short*)(wsb + XB_OFF);
    unsigned short* Yb = (unsigned short*)(wsb + YB_OFF);
    float* fws = (float*)(wsb + FW_OFF);
    int wid = threadIdx.x >> 6, lane = threadIdx.x & 63;
    int row = blockIdx.x * 4 + wid;
    float curv = __expf(curv_log[0]);
    const float* src; unsigned short* dst; float alpha; int idx; int is_text;
    if (row < MM) {
        src = X + (size_t)row * DD; dst = Xb + (size_t)row * DD;
        alpha = __expf(ta_log[0]); idx = row; is_text = 1;
    } else {
        int r = row - MM;
        src = Y + (size_t)r * DD; dst = Yb + (size_t)r * DD;
        alpha = __expf(la_log[0]); idx = r; is_text = 0;
    }
    float n2 = 0.f;
    #pragma unroll
    for (int j = 0; j < 3; ++j) {
        float4 v = *(const float4*)(src + lane * 4 + 256 * j);
        n2 += v.x * v.x + v.y * v.y + v.z * v.z + v.w * v.w;
        u16x4 o; o[0] = f2bf(v.x); o[1] = f2bf(v.y); o[2] = f2bf(v.z); o[3] = f2bf(v.w);
        *(u16x4*)(dst + lane * 4 + 256 * j) = o;
    }
    #pragma unroll
    for (int m = 32; m; m >>= 1) n2 += __shfl_xor(n2, m);
    if (lane == 0) {
        float r = sqrtf(curv) * alpha * sqrtf(n2);
        float s = alpha * sinhf(r) / fmaxf(r, EPSF);
        float tt = sqrtf(1.0f / curv + s * s * n2);
        if (is_text) {
            fws[S_T + idx] = s; fws[T_T + idx] = tt; fws[CA_T + idx] = tt / s;
        } else {
            fws[S_L + idx] = s; fws[T_L + idx] = tt;
        }
    }
}

// ---------------- pos: exact fp32 positive distance ----------------
__global__ void pos_kernel(const float* __restrict__ X, const float* __restrict__ Y,
                           const int* __restrict__ tgt, const float* curv_log,
                           char* __restrict__ wsb) {
    float* fws = (float*)(wsb + FW_OFF);
    int wid = threadIdx.x >> 6, lane = threadIdx.x & 63;
    int row = blockIdx.x * 4 + wid;
    if (row >= MM) return;
    float curv = __expf(curv_log[0]);
    int t = tgt[row];
    const float* xr = X + (size_t)row * DD;
    const float* yr = Y + (size_t)t * DD;
    float dot = 0.f;
    #pragma unroll
    for (int k = 0; k < DD / 64; ++k) dot += xr[lane + 64 * k] * yr[lane + 64 * k];
    #pragma unroll
    for (int m = 32; m; m >>= 1) dot += __shfl_xor(dot, m);
    if (lane == 0) {
        float inner = fws[S_T + row] * fws[S_L + t] * dot - fws[T_T + row] * fws[T_L + t];
        float cd = fmaxf(-curv * inner, 1.0f + EPSF);
        float d = __logf(cd + sqrtf(cd * cd - 1.0f)) * rsqrtf(curv);
        fws[POS + row] = d;
    }
}

// ---------------- main: 256x256, 24 phases of 16x mfma_32x32x16, 4-region ring ----------------
__global__ __launch_bounds__(TPB) void main_kernel(
    const int* __restrict__ tgt, char* __restrict__ wsb)
{
    // region rg = [row 0..255][k-octet 0..3] 64B rows, 16KB; octet stored at slot (o ^ (row&3)).
    __shared__ unsigned short Ald[4 * 8192];   // 64KB
    __shared__ unsigned short Bld[4 * 8192];   // 64KB
    __shared__ float red[256][4][2];           // 8KB

    const unsigned short* Xb = (const unsigned short*)(wsb + XB_OFF);
    const unsigned short* Yb = (const unsigned short*)(wsb + YB_OFF);
    float* fws = (float*)(wsb + FW_OFF);

    int tid = threadIdx.x;
    int lane = tid & 63, wid = tid >> 6;
    int wr = wid >> 2, wc = wid & 3;           // 2 row-groups x 4 col-groups of waves
    int l31 = lane & 31, hl = lane >> 5;

    // XCD-bijective swizzle: 512 blocks
    int bid = blockIdx.x;
    int pos = bid >> 3;
    int coltile = pos >> 2;                    // 0..15
    int rowpanel = (bid & 7) * 4 + (pos & 3);  // 0..31
    int rowbase = rowpanel * BM;
    int colbase = coltile * BN;

    // staging: LDS 16B-slot t holds row = t>>2, octet = (t&3) ^ ((t>>2)&3); thread t also does row+128
    int ko_src = ((tid & 3) ^ ((tid >> 2) & 3)) * 8;
    const unsigned short* xk = Xb + (size_t)(rowbase + (tid >> 2)) * DD + ko_src;
    const unsigned short* yk = Yb + (size_t)(colbase + (tid >> 2)) * DD + ko_src;
    unsigned short* adst = Ald + tid * 8;
    unsigned short* bdst = Bld + tid * 8;

#define STG_AB(OFF, RG) do { \
    gll16(xk + (OFF), adst + (RG) * 8192); \
    gll16(xk + (size_t)128 * DD + (OFF), adst + (RG) * 8192 + 4096); \
    gll16(yk + (OFF), bdst + (RG) * 8192); \
    gll16(yk + (size_t)128 * DD + (OFF), bdst + (RG) * 8192 + 4096); } while (0)

    // fragment read bases: operand lane holds row/col = l31, k-octet o = h*2 + hl.
    // swizzled addr = row*64 + ((o ^ (row&3))<<4); with r_lo=row&1, r_hi=(row>>1)&1:
    //   = row*64 + ((h^r_hi)<<5) + ((hl^r_lo)<<4);  h=1 base = h=0 base XOR 32.
    unsigned a_b0 = (unsigned)(uintptr_t)(&Ald[0]) + (wr * 128 + l31) * 64
                    + (((l31 >> 1) & 1) << 5) + ((hl ^ (l31 & 1)) << 4);
    unsigned a_b1 = a_b0 ^ 32;
    unsigned b_b0 = (unsigned)(uintptr_t)(&Bld[0]) + (wc * 64 + l31) * 64
                    + (((l31 >> 1) & 1) << 5) + ((hl ^ (l31 & 1)) << 4);
    unsigned b_b1 = b_b0 ^ 32;

    f32x16 acc[4][2];
    #pragma unroll
    for (int a = 0; a < 4; ++a)
        #pragma unroll
        for (int b = 0; b < 2; ++b)
            acc[a][b] = (f32x16)(0.f);

    short8 af[4][2], bf[2][2];

    // phase: reads(rg) -> STG(rg+3) -> VM8 (drains stage p-2: covers NEXT phase's reads,
    // published by the two barriers between) -> BAR -> lgkm0 -> 16 MFMA -> BAR
#define PH(RG, STG, W) do { \
    DSR(bf[0][0], b_b0, (RG) * 16384 + 0); \
    DSR(bf[0][1], b_b1, (RG) * 16384 + 0); \
    DSR(bf[1][0], b_b0, (RG) * 16384 + 2048); \
    DSR(bf[1][1], b_b1, (RG) * 16384 + 2048); \
    DSR(af[0][0], a_b0, (RG) * 16384 + 0); \
    DSR(af[0][1], a_b1, (RG) * 16384 + 0); \
    DSR(af[1][0], a_b0, (RG) * 16384 + 2048); \
    DSR(af[1][1], a_b1, (RG) * 16384 + 2048); \
    DSR(af[2][0], a_b0, (RG) * 16384 + 4096); \
    DSR(af[2][1], a_b1, (RG) * 16384 + 4096); \
    DSR(af[3][0], a_b0, (RG) * 16384 + 6144); \
    DSR(af[3][1], a_b1, (RG) * 16384 + 6144); \
    STG; \
    W; \
    BAR(); \
    asm volatile("s_waitcnt lgkmcnt(0)" ::: "memory"); \
    __builtin_amdgcn_sched_barrier(0); \
    __builtin_amdgcn_s_setprio(1); \
    _Pragma("unroll") \
    for (int mf = 0; mf < 4; ++mf) { \
        acc[mf][0] = MFMA32(af[mf][0], bf[0][0], acc[mf][0]); \
        acc[mf][1] = MFMA32(af[mf][0], bf[1][0], acc[mf][1]); \
    } \
    _Pragma("unroll") \
    for (int mf = 0; mf < 4; ++mf) { \
        acc[mf][0] = MFMA32(af[mf][1], bf[0][1], acc[mf][0]); \
        acc[mf][1] = MFMA32(af[mf][1], bf[1][1], acc[mf][1]); \
    } \
    __builtin_amdgcn_s_setprio(0); \
    BAR(); \
} while (0)

    // prologue: stage regions 0,1,2 (12 loads); drain rg0; publish
    STG_AB(0, 0); STG_AB(32, 1); STG_AB(64, 2);
    VM8;
    BAR();

    // 5 iters x 4 phases (K-regions 0..19)
    #pragma unroll 1
    for (int kp = 0; kp < 5; ++kp) {
        PH(0, STG_AB(96, 3),  VM8);
        PH(1, STG_AB(128, 0), VM8);
        PH(2, STG_AB(160, 1), VM8);
        PH(3, STG_AB(192, 2), VM8);
        xk += 128; yk += 128;
    }
    // tail: K-regions 20..23
    PH(0, STG_AB(96, 3), VM8);
    PH(1, NOPS, VM8);
    PH(2, NOPS, VM4);
    PH(3, NOPS, VM0);

    // ---- epilogue: per-row top-2 of u = sb*dot - ca*tb (top2 of Lorentz inner; sa>0) ----
    // C/D 32x32: col = l31 (+nf*32), row = (r&3) + 8*(r>>2) + 4*hl (+mf*32)
    int colb = colbase + wc * 64 + l31;
    float sbv[2], tbv[2];
    #pragma unroll
    for (int nf = 0; nf < 2; ++nf) { sbv[nf] = fws[S_L + colb + nf * 32]; tbv[nf] = fws[T_L + colb + nf * 32]; }

    #pragma unroll
    for (int mf = 0; mf < 4; ++mf) {
        float m1[16], m2[16];
        #pragma unroll
        for (int r = 0; r < 16; ++r) {
            int rloc = (r & 3) + 8 * (r >> 2) + 4 * hl;
            int row = rowbase + wr * 128 + mf * 32 + rloc;
            float ca = fws[CA_T + row];
            int tgj = tgt[row];
            float u0 = sbv[0] * acc[mf][0][r] - ca * tbv[0];
            if (colb == tgj) u0 = -3.4e38f;
            float u1 = sbv[1] * acc[mf][1][r] - ca * tbv[1];
            if (colb + 32 == tgj) u1 = -3.4e38f;
            m1[r] = fmaxf(u0, u1);
            m2[r] = fminf(u0, u1);
        }
        #pragma unroll
        for (int mask = 1; mask <= 16; mask <<= 1)
            #pragma unroll
            for (int r = 0; r < 16; ++r) {
                float o1 = __shfl_xor(m1[r], mask);
                float o2 = __shfl_xor(m2[r], mask);
                float n1 = fmaxf(m1[r], o1);
                m2[r] = fmaxf(fminf(m1[r], o1), fmaxf(m2[r], o2));
                m1[r] = n1;
            }
        if (l31 == 0) {
            #pragma unroll
            for (int r = 0; r < 16; ++r) {
                int rl = wr * 128 + mf * 32 + (r & 3) + 8 * (r >> 2) + 4 * hl;
                red[rl][wc][0] = m1[r];
                red[rl][wc][1] = m2[r];
            }
        }
    }
    __syncthreads();
    if (tid < 256) {
        float p1 = -3.4e38f, p2 = -3.4e38f;
        #pragma unroll
        for (int g = 0; g < 4; ++g) {
            float a1 = red[tid][g][0], a2 = red[tid][g][1];
            float n1 = fmaxf(p1, a1);
            p2 = fmaxf(fminf(p1, a1), fmaxf(p2, a2));
            p1 = n1;
        }
        int row = rowbase + tid;
        fws[PART + ((size_t)row * NCOLT + coltile) * 2 + 0] = p1;
        fws[PART + ((size_t)row * NCOLT + coltile) * 2 + 1] = p2;
    }
}

// ---------------- final: merge partials, arccosh on winners, loss ----------------
__global__ void final_kernel(const char* __restrict__ wsb, const float* __restrict__ curv_log,
                             float* __restrict__ out) {
    const float* fws = (const float*)(wsb + FW_OFF);
    int row = blockIdx.x * 256 + threadIdx.x;
    if (row >= MM) return;
    float curv = __expf(curv_log[0]);
    float rsc = rsqrtf(curv);
    const float* p = fws + PART + (size_t)row * (NCOLT * 2);
    float p1 = -3.4e38f, p2 = -3.4e38f;
    #pragma unroll
    for (int s = 0; s < NCOLT; ++s) {
        float a1 = p[s * 2], a2 = p[s * 2 + 1];
        float n1 = fmaxf(p1, a1);
        p2 = fmaxf(fminf(p1, a1), fmaxf(p2, a2));
        p1 = n1;
    }
    float sa = fws[S_T + row];
    float i1 = sa * p1, i2 = sa * p2;          // back to Lorentz inner
    float cd1 = fmaxf(-curv * i1, 1.0f + EPSF);
    float d1 = __logf(cd1 + sqrtf(cd1 * cd1 - 1.0f)) * rsc;
    float cd2 = fmaxf(-curv * i2, 1.0f + EPSF);
    float d2 = __logf(cd2 + sqrtf(cd2 * cd2 - 1.0f)) * rsc;
    float dp = fws[POS + row];
    float denom = __expf(-dp) + __expf(-d1) + __expf(-d2);
    out[row] = __logf(denom) + dp;
}

extern "C" void kernel_launch(void* const* d_in, const int* in_sizes, int n_in,
                              void* d_out, int out_size, void* d_ws, size_t ws_size,
                              hipStream_t stream) {
    const float* X = (const float*)d_in[0];
    const float* Y = (const float*)d_in[1];
    const int* tgt = (const int*)d_in[2];
    const float* curv_log = (const float*)d_in[3];
    const float* ta_log = (const float*)d_in[4];
    const float* la_log = (const float*)d_in[5];
    char* wsb = (char*)d_ws;
    float* out = (float*)d_out;

    prep_conv_kernel<<<(MM + CC) / 4, 256, 0, stream>>>(X, Y, curv_log, ta_log, la_log, wsb);
    pos_kernel<<<MM / 4, 256, 0, stream>>>(X, Y, tgt, curv_log, wsb);
    main_kernel<<<NROWT * NCOLT, TPB, 0, stream>>>(tgt, wsb);
    final_kernel<<<MM / 256, 256, 0, stream>>>(wsb, curv_log, out);
}

// Round 11
// 90.618 us; speedup vs baseline: 1.3073x; 1.3073x over previous
//
#include <hip/hip_runtime.h>
#include <hip/hip_bf16.h>
#include <math.h>

#define MM 8192
#define CC 4096
#define DD 768
#define EPSF 1e-8f

#define BM 256
#define BN 256
#define BK 64
#define TPB 512
#define NKT (DD / BK)          // 12 K-tiles
#define NROWT (MM / BM)        // 32
#define NCOLT (CC / BN)        // 16

// ---- ws layout ----
#define XB_OFF 0
#define YB_OFF (MM * DD * 2)
#define FW_OFF (YB_OFF + CC * DD * 2)
#define S_T 0
#define T_T (MM)
#define S_L (2 * MM)
#define T_L (2 * MM + CC)
#define CA_T (2 * MM + 2 * CC)         // t_t / s_t per text row
#define POS  (CA_T + MM)
#define PART (POS + MM)                // MM * NCOLT * 2 floats (top-2 largest u)

typedef __attribute__((ext_vector_type(8))) short short8;
typedef __attribute__((ext_vector_type(4))) unsigned short u16x4;
typedef __attribute__((ext_vector_type(4))) float f32x4;

__device__ inline unsigned short f2bf(float f) {
    unsigned int u = __float_as_uint(f);
    u += 0x7FFF + ((u >> 16) & 1);   // RNE
    return (unsigned short)(u >> 16);
}

__device__ inline void gll16(const void* g, void* l) {
    __builtin_amdgcn_global_load_lds(
        (const __attribute__((address_space(1))) void*)(uintptr_t)g,
        (__attribute__((address_space(3))) void*)(unsigned)(uintptr_t)l,
        16, 0, 0);
}

#define BAR() do { __builtin_amdgcn_sched_barrier(0); __builtin_amdgcn_s_barrier(); __builtin_amdgcn_sched_barrier(0); } while (0)
#define VM8 asm volatile("s_waitcnt vmcnt(8)" ::: "memory")
#define VM4 asm volatile("s_waitcnt vmcnt(4)" ::: "memory")
#define VM0 asm volatile("s_waitcnt vmcnt(0)" ::: "memory")
#define NOPS ((void)0)

#define DSR(dst, base, off) \
    asm volatile("ds_read_b128 %0, %1 offset:%c2" : "=v"(dst) : "v"(base), "n"(off))

#define MFMA_B(a, b, c) __builtin_amdgcn_mfma_f32_16x16x32_bf16((a), (b), (c), 0, 0, 0)

// ---------------- prep+convert: per-row s,t,ca + bf16 copies (NONTEMPORAL stores:
// lines land clean in MALL/HBM, no dirty L2 state -> main's staging reads are clean) ------
__global__ void prep_conv_kernel(const float* __restrict__ X, const float* __restrict__ Y,
                                 const float* curv_log, const float* ta_log, const float* la_log,
                                 char* __restrict__ wsb) {
    unsigned short* Xb = (unsigned short*)(wsb + XB_OFF);
    unsigned short* Yb = (unsigned short*)(wsb + YB_OFF);
    float* fws = (float*)(wsb + FW_OFF);
    int wid = threadIdx.x >> 6, lane = threadIdx.x & 63;
    int row = blockIdx.x * 4 + wid;
    float curv = __expf(curv_log[0]);
    const float* src; unsigned short* dst; float alpha; int idx; int is_text;
    if (row < MM) {
        src = X + (size_t)row * DD; dst = Xb + (size_t)row * DD;
        alpha = __expf(ta_log[0]); idx = row; is_text = 1;
    } else {
        int r = row - MM;
        src = Y + (size_t)r * DD; dst = Yb + (size_t)r * DD;
        alpha = __expf(la_log[0]); idx = r; is_text = 0;
    }
    float n2 = 0.f;
    #pragma unroll
    for (int j = 0; j < 3; ++j) {
        float4 v = *(const float4*)(src + lane * 4 + 256 * j);
        n2 += v.x * v.x + v.y * v.y + v.z * v.z + v.w * v.w;
        unsigned long long pk =
            (unsigned long long)f2bf(v.x)
          | ((unsigned long long)f2bf(v.y) << 16)
          | ((unsigned long long)f2bf(v.z) << 32)
          | ((unsigned long long)f2bf(v.w) << 48);
        __builtin_nontemporal_store(pk, (unsigned long long*)(dst + lane * 4 + 256 * j));
    }
    #pragma unroll
    for (int m = 32; m; m >>= 1) n2 += __shfl_xor(n2, m);
    if (lane == 0) {
        float r = sqrtf(curv) * alpha * sqrtf(n2);
        float s = alpha * sinhf(r) / fmaxf(r, EPSF);
        float tt = sqrtf(1.0f / curv + s * s * n2);
        if (is_text) {
            fws[S_T + idx] = s; fws[T_T + idx] = tt; fws[CA_T + idx] = tt / s;
        } else {
            fws[S_L + idx] = s; fws[T_L + idx] = tt;
        }
    }
}

// ---------------- pos: exact fp32 positive distance ----------------
__global__ void pos_kernel(const float* __restrict__ X, const float* __restrict__ Y,
                           const int* __restrict__ tgt, const float* curv_log,
                           char* __restrict__ wsb) {
    float* fws = (float*)(wsb + FW_OFF);
    int wid = threadIdx.x >> 6, lane = threadIdx.x & 63;
    int row = blockIdx.x * 4 + wid;
    if (row >= MM) return;
    float curv = __expf(curv_log[0]);
    int t = tgt[row];
    const float* xr = X + (size_t)row * DD;
    const float* yr = Y + (size_t)t * DD;
    float dot = 0.f;
    #pragma unroll
    for (int k = 0; k < DD / 64; ++k) dot += xr[lane + 64 * k] * yr[lane + 64 * k];
    #pragma unroll
    for (int m = 32; m; m >>= 1) dot += __shfl_xor(dot, m);
    if (lane == 0) {
        float inner = fws[S_T + row] * fws[S_L + t] * dot - fws[T_T + row] * fws[T_L + t];
        float cd = fmaxf(-curv * inner, 1.0f + EPSF);
        float d = __logf(cd + sqrtf(cd * cd - 1.0f)) * rsqrtf(curv);
        fws[POS + row] = d;
    }
}

// ---------------- main: 256x256 8-phase, XOR-swizzled row-major LDS, counted vmcnt ----------------
__global__ __launch_bounds__(TPB) void main_kernel(
    const int* __restrict__ tgt, char* __restrict__ wsb)
{
    // region rg = (kt&1)*2 + kh; [row 0..255][k-slot 0..3] 64B rows, 16KB.
    // XOR swizzle: byte = row*64 + (slot*16 ^ ((row>>1)&3)<<4) -> 2-way banks on ds_read_b128.
    __shared__ unsigned short Ald[4 * 8192];   // 64KB
    __shared__ unsigned short Bld[4 * 8192];   // 64KB
    __shared__ float red[256][4][2];           // 8KB

    const unsigned short* Xb = (const unsigned short*)(wsb + XB_OFF);
    const unsigned short* Yb = (const unsigned short*)(wsb + YB_OFF);
    float* fws = (float*)(wsb + FW_OFF);

    int tid = threadIdx.x;
    int lane = tid & 63, wid = tid >> 6;
    int wr = wid >> 2, wc = wid & 3;           // 2 row-groups x 4 col-groups
    int l15 = lane & 15, rgrp = lane >> 4;

    // XCD-bijective swizzle: 512 blocks
    int bid = blockIdx.x;
    int pos = bid >> 3;
    int coltile = pos >> 2;                    // 0..15
    int rowpanel = (bid & 7) * 4 + (pos & 3);  // 0..31
    int rowbase = rowpanel * BM;
    int colbase = coltile * BN;

    // staging: LDS slot t (16B, linear) holds row = t>>2, k-octet = (t&3) ^ ((t>>3)&3)
    int ko_src = ((tid & 3) ^ ((tid >> 3) & 3)) * 8;
    const unsigned short* xk = Xb + (size_t)(rowbase + (tid >> 2)) * DD + ko_src;
    const unsigned short* yk = Yb + (size_t)(colbase + (tid >> 2)) * DD + ko_src;
    unsigned short* adst = Ald + tid * 8;
    unsigned short* bdst = Bld + tid * 8;

#define STG_A(OFF, RG) do { gll16(xk + (OFF), adst + (RG) * 8192); \
                            gll16(xk + (size_t)128 * DD + (OFF), adst + (RG) * 8192 + 4096); } while (0)
#define STG_B(OFF, RG) do { gll16(yk + (OFF), bdst + (RG) * 8192); \
                            gll16(yk + (size_t)128 * DD + (OFF), bdst + (RG) * 8192 + 4096); } while (0)

    // fragment read bases with read-side XOR folded in (per-lane constant)
    unsigned a_base = (unsigned)(uintptr_t)(&Ald[0]) + (wr * 128 + l15) * 64
                      + ((rgrp * 16) ^ (((l15 >> 1) & 3) << 4));
    unsigned b_base = (unsigned)(uintptr_t)(&Bld[0]) + (wc * 64 + l15) * 64
                      + ((rgrp * 16) ^ (((l15 >> 1) & 3) << 4));

    f32x4 acc[8][4];
    #pragma unroll
    for (int a = 0; a < 8; ++a)
        #pragma unroll
        for (int b = 0; b < 4; ++b)
            acc[a][b] = (f32x4){0.f, 0.f, 0.f, 0.f};

    short8 af[4], bf[4];

#define MF16(AO) do { \
    acc[(AO)+0][0] = MFMA_B(af[0], bf[0], acc[(AO)+0][0]); \
    acc[(AO)+0][1] = MFMA_B(af[0], bf[1], acc[(AO)+0][1]); \
    acc[(AO)+0][2] = MFMA_B(af[0], bf[2], acc[(AO)+0][2]); \
    acc[(AO)+0][3] = MFMA_B(af[0], bf[3], acc[(AO)+0][3]); \
    acc[(AO)+1][0] = MFMA_B(af[1], bf[0], acc[(AO)+1][0]); \
    acc[(AO)+1][1] = MFMA_B(af[1], bf[1], acc[(AO)+1][1]); \
    acc[(AO)+1][2] = MFMA_B(af[1], bf[2], acc[(AO)+1][2]); \
    acc[(AO)+1][3] = MFMA_B(af[1], bf[3], acc[(AO)+1][3]); \
    acc[(AO)+2][0] = MFMA_B(af[2], bf[0], acc[(AO)+2][0]); \
    acc[(AO)+2][1] = MFMA_B(af[2], bf[1], acc[(AO)+2][1]); \
    acc[(AO)+2][2] = MFMA_B(af[2], bf[2], acc[(AO)+2][2]); \
    acc[(AO)+2][3] = MFMA_B(af[2], bf[3], acc[(AO)+2][3]); \
    acc[(AO)+3][0] = MFMA_B(af[3], bf[0], acc[(AO)+3][0]); \
    acc[(AO)+3][1] = MFMA_B(af[3], bf[1], acc[(AO)+3][1]); \
    acc[(AO)+3][2] = MFMA_B(af[3], bf[2], acc[(AO)+3][2]); \
    acc[(AO)+3][3] = MFMA_B(af[3], bf[3], acc[(AO)+3][3]); \
} while (0)

#define PHASE(RG, MH, AO, STG, W) do { \
    if ((MH) == 0) { \
        DSR(bf[0], b_base, (RG) * 16384 + 0); \
        DSR(bf[1], b_base, (RG) * 16384 + 1024); \
        DSR(bf[2], b_base, (RG) * 16384 + 2048); \
        DSR(bf[3], b_base, (RG) * 16384 + 3072); \
    } \
    DSR(af[0], a_base, (RG) * 16384 + ((MH) * 4 + 0) * 1024); \
    DSR(af[1], a_base, (RG) * 16384 + ((MH) * 4 + 1) * 1024); \
    DSR(af[2], a_base, (RG) * 16384 + ((MH) * 4 + 2) * 1024); \
    DSR(af[3], a_base, (RG) * 16384 + ((MH) * 4 + 3) * 1024); \
    STG; \
    W; \
    BAR(); \
    asm volatile("s_waitcnt lgkmcnt(0)" ::: "memory"); \
    __builtin_amdgcn_sched_barrier(0); \
    __builtin_amdgcn_s_setprio(1); \
    MF16(AO); \
    __builtin_amdgcn_s_setprio(0); \
    BAR(); \
} while (0)

    // prologue: stage rg0(A,B), rg1(A,B), rg2(A,B) = 12 loads; drain rg0
    STG_A(0, 0);  STG_B(0, 0);
    STG_A(32, 1); STG_B(32, 1);
    STG_A(64, 2); STG_B(64, 2);
    VM8;
    BAR();

    // 5 full pairs (kt = 0,2,4,6,8)
    #pragma unroll 1
    for (int kp = 0; kp < 5; ++kp) {
        PHASE(0, 0, 0, STG_A(96, 3),  NOPS);
        PHASE(0, 1, 4, STG_B(96, 3),  VM8);
        PHASE(1, 0, 0, STG_A(128, 0), NOPS);
        PHASE(1, 1, 4, STG_B(128, 0), VM8);
        PHASE(2, 0, 0, STG_A(160, 1), NOPS);
        PHASE(2, 1, 4, STG_B(160, 1), VM8);
        PHASE(3, 0, 0, STG_A(192, 2), NOPS);
        PHASE(3, 1, 4, STG_B(192, 2), VM8);
        xk += 128; yk += 128;
    }
    // tail pair (kt = 10,11)
    PHASE(0, 0, 0, STG_A(96, 3), NOPS);
    PHASE(0, 1, 4, STG_B(96, 3), VM8);
    PHASE(1, 0, 0, NOPS, NOPS);
    PHASE(1, 1, 4, NOPS, VM4);
    PHASE(2, 0, 0, NOPS, NOPS);
    PHASE(2, 1, 4, NOPS, VM0);
    PHASE(3, 0, 0, NOPS, NOPS);
    PHASE(3, 1, 4, NOPS, NOPS);

    // ---- epilogue: per-row top-2 of u = sb*dot - ca*tb (argtop2 == top2 of inner; sa>0) ----
    int colb = colbase + wc * 64 + l15;
    float sbv[4], tbv[4];
    #pragma unroll
    for (int nf = 0; nf < 4; ++nf) { sbv[nf] = fws[S_L + colb + nf * 16]; tbv[nf] = fws[T_L + colb + nf * 16]; }

    float m1[32], m2[32];
    #pragma unroll
    for (int mf = 0; mf < 8; ++mf) {
        int rw = rowbase + wr * 128 + mf * 16 + rgrp * 4;
        #pragma unroll
        for (int j = 0; j < 4; ++j) {
            float ca = fws[CA_T + rw + j];
            int tgj = tgt[rw + j];
            float a = -3.4e38f, b = -3.4e38f;
            #pragma unroll
            for (int nf = 0; nf < 4; ++nf) {
                float u = sbv[nf] * acc[mf][nf][j] - ca * tbv[nf];
                if (colb + nf * 16 == tgj) u = -3.4e38f;
                float n1 = fmaxf(a, u);
                b = fmaxf(b, fminf(a, u));
                a = n1;
            }
            m1[mf * 4 + j] = a; m2[mf * 4 + j] = b;
        }
    }
    #pragma unroll
    for (int mask = 1; mask <= 8; mask <<= 1)
        #pragma unroll
        for (int i = 0; i < 32; ++i) {
            float o1 = __shfl_xor(m1[i], mask);
            float o2 = __shfl_xor(m2[i], mask);
            float n1 = fmaxf(m1[i], o1);
            m2[i] = fmaxf(fminf(m1[i], o1), fmaxf(m2[i], o2));
            m1[i] = n1;
        }
    if (l15 == 0) {
        #pragma unroll
        for (int mf = 0; mf < 8; ++mf)
            #pragma unroll
            for (int j = 0; j < 4; ++j) {
                int rl = wr * 128 + mf * 16 + rgrp * 4 + j;
                red[rl][wc][0] = m1[mf * 4 + j];
                red[rl][wc][1] = m2[mf * 4 + j];
            }
    }
    __syncthreads();
    if (tid < 256) {
        float p1 = -3.4e38f, p2 = -3.4e38f;
        #pragma unroll
        for (int g = 0; g < 4; ++g) {
            float a1 = red[tid][g][0], a2 = red[tid][g][1];
            float n1 = fmaxf(p1, a1);
            p2 = fmaxf(fminf(p1, a1), fmaxf(p2, a2));
            p1 = n1;
        }
        int row = rowbase + tid;
        fws[PART + ((size_t)row * NCOLT + coltile) * 2 + 0] = p1;
        fws[PART + ((size_t)row * NCOLT + coltile) * 2 + 1] = p2;
    }
}

// ---------------- final: merge partials, arccosh on winners, loss ----------------
__global__ void final_kernel(const char* __restrict__ wsb, const float* __restrict__ curv_log,
                             float* __restrict__ out) {
    const float* fws = (const float*)(wsb + FW_OFF);
    int row = blockIdx.x * 256 + threadIdx.x;
    if (row >= MM) return;
    float curv = __expf(curv_log[0]);
    float rsc = rsqrtf(curv);
    const float* p = fws + PART + (size_t)row * (NCOLT * 2);
    float p1 = -3.4e38f, p2 = -3.4e38f;
    #pragma unroll
    for (int s = 0; s < NCOLT; ++s) {
        float a1 = p[s * 2], a2 = p[s * 2 + 1];
        float n1 = fmaxf(p1, a1);
        p2 = fmaxf(fminf(p1, a1), fmaxf(p2, a2));
        p1 = n1;
    }
    float sa = fws[S_T + row];
    float i1 = sa * p1, i2 = sa * p2;          // back to Lorentz inner
    float cd1 = fmaxf(-curv * i1, 1.0f + EPSF);
    float d1 = __logf(cd1 + sqrtf(cd1 * cd1 - 1.0f)) * rsc;
    float cd2 = fmaxf(-curv * i2, 1.0f + EPSF);
    float d2 = __logf(cd2 + sqrtf(cd2 * cd2 - 1.0f)) * rsc;
    float dp = fws[POS + row];
    float denom = __expf(-dp) + __expf(-d1) + __expf(-d2);
    out[row] = __logf(denom) + dp;
}

extern "C" void kernel_launch(void* const* d_in, const int* in_sizes, int n_in,
                              void* d_out, int out_size, void* d_ws, size_t ws_size,
                              hipStream_t stream) {
    const float* X = (const float*)d_in[0];
    const float* Y = (const float*)d_in[1];
    const int* tgt = (const int*)d_in[2];
    const float* curv_log = (const float*)d_in[3];
    const float* ta_log = (const float*)d_in[4];
    const float* la_log = (const float*)d_in[5];
    char* wsb = (char*)d_ws;
    float* out = (float*)d_out;

    prep_conv_kernel<<<(MM + CC) / 4, 256, 0, stream>>>(X, Y, curv_log, ta_log, la_log, wsb);
    pos_kernel<<<MM / 4, 256, 0, stream>>>(X, Y, tgt, curv_log, wsb);
    main_kernel<<<NROWT * NCOLT, TPB, 0, stream>>>(tgt, wsb);
    final_kernel<<<MM / 256, 256, 0, stream>>>(wsb, curv_log, out);
}

// Round 12
// 89.520 us; speedup vs baseline: 1.3234x; 1.0123x over previous
//
#include <hip/hip_runtime.h>
#include <hip/hip_bf16.h>
#include <math.h>

#define MM 8192
#define CC 4096
#define DD 768
#define EPSF 1e-8f

#define BM 256
#define BN 256
#define TPB 512
#define NROWT (MM / BM)        // 32
#define NCOLT (CC / BN)        // 16

// ---- ws layout ----
#define XB_OFF 0
#define YB_OFF (MM * DD * 2)
#define FW_OFF (YB_OFF + CC * DD * 2)
#define S_T 0
#define T_T (MM)
#define S_L (2 * MM)
#define T_L (2 * MM + CC)
#define CA_T (2 * MM + 2 * CC)         // t_t / s_t per text row
#define POS  (CA_T + MM)               // raw u at the positive label (written by main epilogue)
#define PART (POS + MM)                // MM * NCOLT * 2 floats (top-2 largest u)

typedef __attribute__((ext_vector_type(8))) short short8;
typedef __attribute__((ext_vector_type(4))) unsigned short u16x4;
typedef __attribute__((ext_vector_type(4))) float f32x4;

__device__ inline unsigned short f2bf(float f) {
    unsigned int u = __float_as_uint(f);
    u += 0x7FFF + ((u >> 16) & 1);   // RNE
    return (unsigned short)(u >> 16);
}

__device__ inline void gll16(const void* g, void* l) {
    __builtin_amdgcn_global_load_lds(
        (const __attribute__((address_space(1))) void*)(uintptr_t)g,
        (__attribute__((address_space(3))) void*)(unsigned)(uintptr_t)l,
        16, 0, 0);
}

#define BAR() do { __builtin_amdgcn_sched_barrier(0); __builtin_amdgcn_s_barrier(); __builtin_amdgcn_sched_barrier(0); } while (0)
#define VM8 asm volatile("s_waitcnt vmcnt(8)" ::: "memory")
#define VM4 asm volatile("s_waitcnt vmcnt(4)" ::: "memory")
#define VM0 asm volatile("s_waitcnt vmcnt(0)" ::: "memory")
#define NOPS ((void)0)

#define DSR(dst, base, off) \
    asm volatile("ds_read_b128 %0, %1 offset:%c2" : "=v"(dst) : "v"(base), "n"(off))

#define MFMA_B(a, b, c) __builtin_amdgcn_mfma_f32_16x16x32_bf16((a), (b), (c), 0, 0, 0)

// ---------------- prep+convert: per-row s,t,ca + bf16 copies ----------------
__global__ void prep_conv_kernel(const float* __restrict__ X, const float* __restrict__ Y,
                                 const float* curv_log, const float* ta_log, const float* la_log,
                                 char* __restrict__ wsb) {
    unsigned short* Xb = (unsigned short*)(wsb + XB_OFF);
    unsigned short* Yb = (unsigned short*)(wsb + YB_OFF);
    float* fws = (float*)(wsb + FW_OFF);
    int wid = threadIdx.x >> 6, lane = threadIdx.x & 63;
    int row = blockIdx.x * 4 + wid;
    float curv = __expf(curv_log[0]);
    const float* src; unsigned short* dst; float alpha; int idx; int is_text;
    if (row < MM) {
        src = X + (size_t)row * DD; dst = Xb + (size_t)row * DD;
        alpha = __expf(ta_log[0]); idx = row; is_text = 1;
    } else {
        int r = row - MM;
        src = Y + (size_t)r * DD; dst = Yb + (size_t)r * DD;
        alpha = __expf(la_log[0]); idx = r; is_text = 0;
    }
    float n2 = 0.f;
    #pragma unroll
    for (int j = 0; j < 3; ++j) {
        float4 v = *(const float4*)(src + lane * 4 + 256 * j);
        n2 += v.x * v.x + v.y * v.y + v.z * v.z + v.w * v.w;
        u16x4 o; o[0] = f2bf(v.x); o[1] = f2bf(v.y); o[2] = f2bf(v.z); o[3] = f2bf(v.w);
        *(u16x4*)(dst + lane * 4 + 256 * j) = o;
    }
    #pragma unroll
    for (int m = 32; m; m >>= 1) n2 += __shfl_xor(n2, m);
    if (lane == 0) {
        float r = sqrtf(curv) * alpha * sqrtf(n2);
        float s = alpha * sinhf(r) / fmaxf(r, EPSF);
        float tt = sqrtf(1.0f / curv + s * s * n2);
        if (is_text) {
            fws[S_T + idx] = s; fws[T_T + idx] = tt; fws[CA_T + idx] = tt / s;
        } else {
            fws[S_L + idx] = s; fws[T_L + idx] = tt;
        }
    }
}

// ---------------- main: 256x256, 24 merged phases (32 MFMA each), 4-region ring ----------------
__global__ __launch_bounds__(TPB) void main_kernel(
    const int* __restrict__ tgt, char* __restrict__ wsb)
{
    // region rg: [row 0..255][k-slot 0..3] 64B rows, 16KB; slot s of row r holds
    // octet s ^ ((r>>1)&3) (R6 verified swizzle, conflict-free on ds_read_b128).
    __shared__ unsigned short Ald[4 * 8192];   // 64KB
    __shared__ unsigned short Bld[4 * 8192];   // 64KB
    __shared__ float red[256][4][2];           // 8KB

    const unsigned short* Xb = (const unsigned short*)(wsb + XB_OFF);
    const unsigned short* Yb = (const unsigned short*)(wsb + YB_OFF);
    float* fws = (float*)(wsb + FW_OFF);

    int tid = threadIdx.x;
    int lane = tid & 63, wid = tid >> 6;
    int wr = wid >> 2, wc = wid & 3;           // 2 row-groups x 4 col-groups
    int l15 = lane & 15, rgrp = lane >> 4;

    // XCD-bijective swizzle: 512 blocks
    int bid = blockIdx.x;
    int pos = bid >> 3;
    int coltile = pos >> 2;                    // 0..15
    int rowpanel = (bid & 7) * 4 + (pos & 3);  // 0..31
    int rowbase = rowpanel * BM;
    int colbase = coltile * BN;

    // staging: LDS slot t (16B, linear) holds row = t>>2, k-octet = (t&3) ^ ((t>>3)&3)
    int ko_src = ((tid & 3) ^ ((tid >> 3) & 3)) * 8;
    const unsigned short* xk = Xb + (size_t)(rowbase + (tid >> 2)) * DD + ko_src;
    const unsigned short* yk = Yb + (size_t)(colbase + (tid >> 2)) * DD + ko_src;
    unsigned short* adst = Ald + tid * 8;
    unsigned short* bdst = Bld + tid * 8;

#define STG_AB(OFF, RG) do { \
    gll16(xk + (OFF), adst + (RG) * 8192); \
    gll16(xk + (size_t)128 * DD + (OFF), adst + (RG) * 8192 + 4096); \
    gll16(yk + (OFF), bdst + (RG) * 8192); \
    gll16(yk + (size_t)128 * DD + (OFF), bdst + (RG) * 8192 + 4096); } while (0)

    // fragment read bases with read-side XOR folded in (per-lane constant)
    unsigned a_base = (unsigned)(uintptr_t)(&Ald[0]) + (wr * 128 + l15) * 64
                      + ((rgrp * 16) ^ (((l15 >> 1) & 3) << 4));
    unsigned b_base = (unsigned)(uintptr_t)(&Bld[0]) + (wc * 64 + l15) * 64
                      + ((rgrp * 16) ^ (((l15 >> 1) & 3) << 4));

    f32x4 acc[8][4];
    #pragma unroll
    for (int a = 0; a < 8; ++a)
        #pragma unroll
        for (int b = 0; b < 4; ++b)
            acc[a][b] = (f32x4){0.f, 0.f, 0.f, 0.f};

    short8 af[8], bf[4];

    // merged phase: 12 ds_reads (full K=32 region) -> stage next region -> counted vmcnt
    // -> BAR -> lgkm0 -> 32 MFMA -> BAR.  2 barriers/phase keeps ring race-free.
#define PH(RG, STG, W) do { \
    DSR(bf[0], b_base, (RG) * 16384 + 0); \
    DSR(bf[1], b_base, (RG) * 16384 + 1024); \
    DSR(bf[2], b_base, (RG) * 16384 + 2048); \
    DSR(bf[3], b_base, (RG) * 16384 + 3072); \
    DSR(af[0], a_base, (RG) * 16384 + 0 * 1024); \
    DSR(af[1], a_base, (RG) * 16384 + 1 * 1024); \
    DSR(af[2], a_base, (RG) * 16384 + 2 * 1024); \
    DSR(af[3], a_base, (RG) * 16384 + 3 * 1024); \
    DSR(af[4], a_base, (RG) * 16384 + 4 * 1024); \
    DSR(af[5], a_base, (RG) * 16384 + 5 * 1024); \
    DSR(af[6], a_base, (RG) * 16384 + 6 * 1024); \
    DSR(af[7], a_base, (RG) * 16384 + 7 * 1024); \
    STG; \
    W; \
    BAR(); \
    asm volatile("s_waitcnt lgkmcnt(0)" ::: "memory"); \
    __builtin_amdgcn_sched_barrier(0); \
    __builtin_amdgcn_s_setprio(1); \
    _Pragma("unroll") \
    for (int mf = 0; mf < 8; ++mf) { \
        acc[mf][0] = MFMA_B(af[mf], bf[0], acc[mf][0]); \
        acc[mf][1] = MFMA_B(af[mf], bf[1], acc[mf][1]); \
        acc[mf][2] = MFMA_B(af[mf], bf[2], acc[mf][2]); \
        acc[mf][3] = MFMA_B(af[mf], bf[3], acc[mf][3]); \
    } \
    __builtin_amdgcn_s_setprio(0); \
    BAR(); \
} while (0)

    // prologue: stage regions 0,1,2 (12 loads); drain rg0; publish
    STG_AB(0, 0); STG_AB(32, 1); STG_AB(64, 2);
    VM8;
    BAR();

    // 5 iters x 4 phases (K = 0..639)
    #pragma unroll 1
    for (int kp = 0; kp < 5; ++kp) {
        PH(0, STG_AB(96, 3),  VM8);
        PH(1, STG_AB(128, 0), VM8);
        PH(2, STG_AB(160, 1), VM8);
        PH(3, STG_AB(192, 2), VM8);
        xk += 128; yk += 128;
    }
    // tail: K = 640..767; waits taper (derivation: ph21 needs ph19's stage -> VM4; ph22 ph20's -> VM0)
    PH(0, STG_AB(96, 3), VM8);
    PH(1, NOPS, VM4);
    PH(2, NOPS, VM0);
    PH(3, NOPS, NOPS);

    // ---- epilogue: per-row top-2 of u = sb*dot - ca*tb; capture positive u, mask it ----
    int colb = colbase + wc * 64 + l15;
    float sbv[4], tbv[4];
    #pragma unroll
    for (int nf = 0; nf < 4; ++nf) { sbv[nf] = fws[S_L + colb + nf * 16]; tbv[nf] = fws[T_L + colb + nf * 16]; }

    float m1[32], m2[32];
    #pragma unroll
    for (int mf = 0; mf < 8; ++mf) {
        int rw = rowbase + wr * 128 + mf * 16 + rgrp * 4;
        #pragma unroll
        for (int j = 0; j < 4; ++j) {
            float ca = fws[CA_T + rw + j];
            int tgj = tgt[rw + j];
            float a = -3.4e38f, b = -3.4e38f;
            #pragma unroll
            for (int nf = 0; nf < 4; ++nf) {
                float u = sbv[nf] * acc[mf][nf][j] - ca * tbv[nf];
                if (colb + nf * 16 == tgj) {
                    fws[POS + rw + j] = u;      // exactly one writer per row grid-wide
                    u = -3.4e38f;
                }
                float n1 = fmaxf(a, u);
                b = fmaxf(b, fminf(a, u));
                a = n1;
            }
            m1[mf * 4 + j] = a; m2[mf * 4 + j] = b;
        }
    }
    #pragma unroll
    for (int mask = 1; mask <= 8; mask <<= 1)
        #pragma unroll
        for (int i = 0; i < 32; ++i) {
            float o1 = __shfl_xor(m1[i], mask);
            float o2 = __shfl_xor(m2[i], mask);
            float n1 = fmaxf(m1[i], o1);
            m2[i] = fmaxf(fminf(m1[i], o1), fmaxf(m2[i], o2));
            m1[i] = n1;
        }
    if (l15 == 0) {
        #pragma unroll
        for (int mf = 0; mf < 8; ++mf)
            #pragma unroll
            for (int j = 0; j < 4; ++j) {
                int rl = wr * 128 + mf * 16 + rgrp * 4 + j;
                red[rl][wc][0] = m1[mf * 4 + j];
                red[rl][wc][1] = m2[mf * 4 + j];
            }
    }
    __syncthreads();
    if (tid < 256) {
        float p1 = -3.4e38f, p2 = -3.4e38f;
        #pragma unroll
        for (int g = 0; g < 4; ++g) {
            float a1 = red[tid][g][0], a2 = red[tid][g][1];
            float n1 = fmaxf(p1, a1);
            p2 = fmaxf(fminf(p1, a1), fmaxf(p2, a2));
            p1 = n1;
        }
        int row = rowbase + tid;
        fws[PART + ((size_t)row * NCOLT + coltile) * 2 + 0] = p1;
        fws[PART + ((size_t)row * NCOLT + coltile) * 2 + 1] = p2;
    }
}

// ---------------- final: merge partials, arccosh on winners + positive, loss ----------------
__global__ void final_kernel(const char* __restrict__ wsb, const float* __restrict__ curv_log,
                             float* __restrict__ out) {
    const float* fws = (const float*)(wsb + FW_OFF);
    int row = blockIdx.x * 256 + threadIdx.x;
    if (row >= MM) return;
    float curv = __expf(curv_log[0]);
    float rsc = rsqrtf(curv);
    const float* p = fws + PART + (size_t)row * (NCOLT * 2);
    float p1 = -3.4e38f, p2 = -3.4e38f;
    #pragma unroll
    for (int s = 0; s < NCOLT; ++s) {
        float a1 = p[s * 2], a2 = p[s * 2 + 1];
        float n1 = fmaxf(p1, a1);
        p2 = fmaxf(fminf(p1, a1), fmaxf(p2, a2));
        p1 = n1;
    }
    float sa = fws[S_T + row];
    float i1 = sa * p1, i2 = sa * p2;              // negatives: back to Lorentz inner
    float ip = sa * fws[POS + row];                // positive inner (captured in main)
    float cd1 = fmaxf(-curv * i1, 1.0f + EPSF);
    float d1 = __logf(cd1 + sqrtf(cd1 * cd1 - 1.0f)) * rsc;
    float cd2 = fmaxf(-curv * i2, 1.0f + EPSF);
    float d2 = __logf(cd2 + sqrtf(cd2 * cd2 - 1.0f)) * rsc;
    float cdp = fmaxf(-curv * ip, 1.0f + EPSF);
    float dp = __logf(cdp + sqrtf(cdp * cdp - 1.0f)) * rsc;
    float denom = __expf(-dp) + __expf(-d1) + __expf(-d2);
    out[row] = __logf(denom) + dp;
}

extern "C" void kernel_launch(void* const* d_in, const int* in_sizes, int n_in,
                              void* d_out, int out_size, void* d_ws, size_t ws_size,
                              hipStream_t stream) {
    const float* X = (const float*)d_in[0];
    const float* Y = (const float*)d_in[1];
    const int* tgt = (const int*)d_in[2];
    const float* curv_log = (const float*)d_in[3];
    const float* ta_log = (const float*)d_in[4];
    const float* la_log = (const float*)d_in[5];
    char* wsb = (char*)d_ws;
    float* out = (float*)d_out;

    prep_conv_kernel<<<(MM + CC) / 4, 256, 0, stream>>>(X, Y, curv_log, ta_log, la_log, wsb);
    main_kernel<<<NROWT * NCOLT, TPB, 0, stream>>>(tgt, wsb);
    final_kernel<<<MM / 256, 256, 0, stream>>>(wsb, curv_log, out);
}

// Round 13
// 88.715 us; speedup vs baseline: 1.3354x; 1.0091x over previous
//
#include <hip/hip_runtime.h>
#include <hip/hip_bf16.h>
#include <math.h>

#define MM 8192
#define CC 4096
#define DD 768
#define EPSF 1e-8f

#define BM 256
#define BN 256
#define BK 64
#define TPB 512
#define NKT (DD / BK)          // 12 K-tiles
#define NROWT (MM / BM)        // 32
#define NCOLT (CC / BN)        // 16

// ---- ws layout ----
#define XB_OFF 0
#define YB_OFF (MM * DD * 2)
#define FW_OFF (YB_OFF + CC * DD * 2)
#define S_T 0
#define T_T (MM)
#define S_L (2 * MM)
#define T_L (2 * MM + CC)
#define CA_T (2 * MM + 2 * CC)         // t_t / s_t per text row
#define POS  (CA_T + MM)               // raw u at the positive label (written by main epilogue)
#define PART (POS + MM)                // MM * NCOLT * 2 floats (top-2 largest u)

typedef __attribute__((ext_vector_type(8))) short short8;
typedef __attribute__((ext_vector_type(4))) unsigned short u16x4;
typedef __attribute__((ext_vector_type(4))) float f32x4;

__device__ inline unsigned short f2bf(float f) {
    unsigned int u = __float_as_uint(f);
    u += 0x7FFF + ((u >> 16) & 1);   // RNE
    return (unsigned short)(u >> 16);
}

__device__ inline void gll16(const void* g, void* l) {
    __builtin_amdgcn_global_load_lds(
        (const __attribute__((address_space(1))) void*)(uintptr_t)g,
        (__attribute__((address_space(3))) void*)(unsigned)(uintptr_t)l,
        16, 0, 0);
}

#define BAR() do { __builtin_amdgcn_sched_barrier(0); __builtin_amdgcn_s_barrier(); __builtin_amdgcn_sched_barrier(0); } while (0)
#define VM8 asm volatile("s_waitcnt vmcnt(8)" ::: "memory")
#define VM4 asm volatile("s_waitcnt vmcnt(4)" ::: "memory")
#define VM0 asm volatile("s_waitcnt vmcnt(0)" ::: "memory")
#define NOPS ((void)0)

#define DSR(dst, base, off) \
    asm volatile("ds_read_b128 %0, %1 offset:%c2" : "=v"(dst) : "v"(base), "n"(off))

#define MFMA_B(a, b, c) __builtin_amdgcn_mfma_f32_16x16x32_bf16((a), (b), (c), 0, 0, 0)

// ---------------- prep+convert: per-row s,t,ca + bf16 copies ----------------
__global__ void prep_conv_kernel(const float* __restrict__ X, const float* __restrict__ Y,
                                 const float* curv_log, const float* ta_log, const float* la_log,
                                 char* __restrict__ wsb) {
    unsigned short* Xb = (unsigned short*)(wsb + XB_OFF);
    unsigned short* Yb = (unsigned short*)(wsb + YB_OFF);
    float* fws = (float*)(wsb + FW_OFF);
    int wid = threadIdx.x >> 6, lane = threadIdx.x & 63;
    int row = blockIdx.x * 4 + wid;
    float curv = __expf(curv_log[0]);
    const float* src; unsigned short* dst; float alpha; int idx; int is_text;
    if (row < MM) {
        src = X + (size_t)row * DD; dst = Xb + (size_t)row * DD;
        alpha = __expf(ta_log[0]); idx = row; is_text = 1;
    } else {
        int r = row - MM;
        src = Y + (size_t)r * DD; dst = Yb + (size_t)r * DD;
        alpha = __expf(la_log[0]); idx = r; is_text = 0;
    }
    float n2 = 0.f;
    #pragma unroll
    for (int j = 0; j < 3; ++j) {
        float4 v = *(const float4*)(src + lane * 4 + 256 * j);
        n2 += v.x * v.x + v.y * v.y + v.z * v.z + v.w * v.w;
        u16x4 o; o[0] = f2bf(v.x); o[1] = f2bf(v.y); o[2] = f2bf(v.z); o[3] = f2bf(v.w);
        *(u16x4*)(dst + lane * 4 + 256 * j) = o;
    }
    #pragma unroll
    for (int m = 32; m; m >>= 1) n2 += __shfl_xor(n2, m);
    if (lane == 0) {
        float r = sqrtf(curv) * alpha * sqrtf(n2);
        float s = alpha * sinhf(r) / fmaxf(r, EPSF);
        float tt = sqrtf(1.0f / curv + s * s * n2);
        if (is_text) {
            fws[S_T + idx] = s; fws[T_T + idx] = tt; fws[CA_T + idx] = tt / s;
        } else {
            fws[S_L + idx] = s; fws[T_L + idx] = tt;
        }
    }
}

// ---------------- main: R6 structure (best: 8-phase split, XOR swizzle) + positive capture ------
__global__ __launch_bounds__(TPB) void main_kernel(
    const int* __restrict__ tgt, char* __restrict__ wsb)
{
    // region rg = (kt&1)*2 + kh; [row 0..255][k-slot 0..3] 64B rows, 16KB.
    // XOR swizzle: byte = row*64 + (slot*16 ^ ((row>>1)&3)<<4) -> 2-way banks on ds_read_b128.
    __shared__ unsigned short Ald[4 * 8192];   // 64KB
    __shared__ unsigned short Bld[4 * 8192];   // 64KB
    __shared__ float red[256][4][2];           // 8KB

    const unsigned short* Xb = (const unsigned short*)(wsb + XB_OFF);
    const unsigned short* Yb = (const unsigned short*)(wsb + YB_OFF);
    float* fws = (float*)(wsb + FW_OFF);

    int tid = threadIdx.x;
    int lane = tid & 63, wid = tid >> 6;
    int wr = wid >> 2, wc = wid & 3;           // 2 row-groups x 4 col-groups
    int l15 = lane & 15, rgrp = lane >> 4;

    // XCD-bijective swizzle: 512 blocks
    int bid = blockIdx.x;
    int pos = bid >> 3;
    int coltile = pos >> 2;                    // 0..15
    int rowpanel = (bid & 7) * 4 + (pos & 3);  // 0..31
    int rowbase = rowpanel * BM;
    int colbase = coltile * BN;

    // staging: LDS slot t (16B, linear) holds row = t>>2, k-octet = (t&3) ^ ((t>>3)&3)
    int ko_src = ((tid & 3) ^ ((tid >> 3) & 3)) * 8;
    const unsigned short* xk = Xb + (size_t)(rowbase + (tid >> 2)) * DD + ko_src;
    const unsigned short* yk = Yb + (size_t)(colbase + (tid >> 2)) * DD + ko_src;
    unsigned short* adst = Ald + tid * 8;
    unsigned short* bdst = Bld + tid * 8;

#define STG_A(OFF, RG) do { gll16(xk + (OFF), adst + (RG) * 8192); \
                            gll16(xk + (size_t)128 * DD + (OFF), adst + (RG) * 8192 + 4096); } while (0)
#define STG_B(OFF, RG) do { gll16(yk + (OFF), bdst + (RG) * 8192); \
                            gll16(yk + (size_t)128 * DD + (OFF), bdst + (RG) * 8192 + 4096); } while (0)

    // fragment read bases with read-side XOR folded in (per-lane constant)
    unsigned a_base = (unsigned)(uintptr_t)(&Ald[0]) + (wr * 128 + l15) * 64
                      + ((rgrp * 16) ^ (((l15 >> 1) & 3) << 4));
    unsigned b_base = (unsigned)(uintptr_t)(&Bld[0]) + (wc * 64 + l15) * 64
                      + ((rgrp * 16) ^ (((l15 >> 1) & 3) << 4));

    f32x4 acc[8][4];
    #pragma unroll
    for (int a = 0; a < 8; ++a)
        #pragma unroll
        for (int b = 0; b < 4; ++b)
            acc[a][b] = (f32x4){0.f, 0.f, 0.f, 0.f};

    short8 af[4], bf[4];

#define MF16(AO) do { \
    acc[(AO)+0][0] = MFMA_B(af[0], bf[0], acc[(AO)+0][0]); \
    acc[(AO)+0][1] = MFMA_B(af[0], bf[1], acc[(AO)+0][1]); \
    acc[(AO)+0][2] = MFMA_B(af[0], bf[2], acc[(AO)+0][2]); \
    acc[(AO)+0][3] = MFMA_B(af[0], bf[3], acc[(AO)+0][3]); \
    acc[(AO)+1][0] = MFMA_B(af[1], bf[0], acc[(AO)+1][0]); \
    acc[(AO)+1][1] = MFMA_B(af[1], bf[1], acc[(AO)+1][1]); \
    acc[(AO)+1][2] = MFMA_B(af[1], bf[2], acc[(AO)+1][2]); \
    acc[(AO)+1][3] = MFMA_B(af[1], bf[3], acc[(AO)+1][3]); \
    acc[(AO)+2][0] = MFMA_B(af[2], bf[0], acc[(AO)+2][0]); \
    acc[(AO)+2][1] = MFMA_B(af[2], bf[1], acc[(AO)+2][1]); \
    acc[(AO)+2][2] = MFMA_B(af[2], bf[2], acc[(AO)+2][2]); \
    acc[(AO)+2][3] = MFMA_B(af[2], bf[3], acc[(AO)+2][3]); \
    acc[(AO)+3][0] = MFMA_B(af[3], bf[0], acc[(AO)+3][0]); \
    acc[(AO)+3][1] = MFMA_B(af[3], bf[1], acc[(AO)+3][1]); \
    acc[(AO)+3][2] = MFMA_B(af[3], bf[2], acc[(AO)+3][2]); \
    acc[(AO)+3][3] = MFMA_B(af[3], bf[3], acc[(AO)+3][3]); \
} while (0)

#define PHASE(RG, MH, AO, STG, W) do { \
    if ((MH) == 0) { \
        DSR(bf[0], b_base, (RG) * 16384 + 0); \
        DSR(bf[1], b_base, (RG) * 16384 + 1024); \
        DSR(bf[2], b_base, (RG) * 16384 + 2048); \
        DSR(bf[3], b_base, (RG) * 16384 + 3072); \
    } \
    DSR(af[0], a_base, (RG) * 16384 + ((MH) * 4 + 0) * 1024); \
    DSR(af[1], a_base, (RG) * 16384 + ((MH) * 4 + 1) * 1024); \
    DSR(af[2], a_base, (RG) * 16384 + ((MH) * 4 + 2) * 1024); \
    DSR(af[3], a_base, (RG) * 16384 + ((MH) * 4 + 3) * 1024); \
    STG; \
    W; \
    BAR(); \
    asm volatile("s_waitcnt lgkmcnt(0)" ::: "memory"); \
    __builtin_amdgcn_sched_barrier(0); \
    __builtin_amdgcn_s_setprio(1); \
    MF16(AO); \
    __builtin_amdgcn_s_setprio(0); \
    BAR(); \
} while (0)

    // prologue: stage rg0(A,B), rg1(A,B), rg2(A,B) = 12 loads; drain rg0
    STG_A(0, 0);  STG_B(0, 0);
    STG_A(32, 1); STG_B(32, 1);
    STG_A(64, 2); STG_B(64, 2);
    VM8;
    BAR();

    // 5 full pairs (kt = 0,2,4,6,8)
    #pragma unroll 1
    for (int kp = 0; kp < 5; ++kp) {
        PHASE(0, 0, 0, STG_A(96, 3),  NOPS);
        PHASE(0, 1, 4, STG_B(96, 3),  VM8);
        PHASE(1, 0, 0, STG_A(128, 0), NOPS);
        PHASE(1, 1, 4, STG_B(128, 0), VM8);
        PHASE(2, 0, 0, STG_A(160, 1), NOPS);
        PHASE(2, 1, 4, STG_B(160, 1), VM8);
        PHASE(3, 0, 0, STG_A(192, 2), NOPS);
        PHASE(3, 1, 4, STG_B(192, 2), VM8);
        xk += 128; yk += 128;
    }
    // tail pair (kt = 10,11)
    PHASE(0, 0, 0, STG_A(96, 3), NOPS);
    PHASE(0, 1, 4, STG_B(96, 3), VM8);
    PHASE(1, 0, 0, NOPS, NOPS);
    PHASE(1, 1, 4, NOPS, VM4);
    PHASE(2, 0, 0, NOPS, NOPS);
    PHASE(2, 1, 4, NOPS, VM0);
    PHASE(3, 0, 0, NOPS, NOPS);
    PHASE(3, 1, 4, NOPS, NOPS);

    // ---- epilogue: per-row top-2 of u = sb*dot - ca*tb; capture positive u, mask it ----
    int colb = colbase + wc * 64 + l15;
    float sbv[4], tbv[4];
    #pragma unroll
    for (int nf = 0; nf < 4; ++nf) { sbv[nf] = fws[S_L + colb + nf * 16]; tbv[nf] = fws[T_L + colb + nf * 16]; }

    float m1[32], m2[32];
    #pragma unroll
    for (int mf = 0; mf < 8; ++mf) {
        int rw = rowbase + wr * 128 + mf * 16 + rgrp * 4;
        #pragma unroll
        for (int j = 0; j < 4; ++j) {
            float ca = fws[CA_T + rw + j];
            int tgj = tgt[rw + j];
            float a = -3.4e38f, b = -3.4e38f;
            #pragma unroll
            for (int nf = 0; nf < 4; ++nf) {
                float u = sbv[nf] * acc[mf][nf][j] - ca * tbv[nf];
                if (colb + nf * 16 == tgj) {
                    fws[POS + rw + j] = u;      // exactly one writer per row grid-wide
                    u = -3.4e38f;
                }
                float n1 = fmaxf(a, u);
                b = fmaxf(b, fminf(a, u));
                a = n1;
            }
            m1[mf * 4 + j] = a; m2[mf * 4 + j] = b;
        }
    }
    #pragma unroll
    for (int mask = 1; mask <= 8; mask <<= 1)
        #pragma unroll
        for (int i = 0; i < 32; ++i) {
            float o1 = __shfl_xor(m1[i], mask);
            float o2 = __shfl_xor(m2[i], mask);
            float n1 = fmaxf(m1[i], o1);
            m2[i] = fmaxf(fminf(m1[i], o1), fmaxf(m2[i], o2));
            m1[i] = n1;
        }
    if (l15 == 0) {
        #pragma unroll
        for (int mf = 0; mf < 8; ++mf)
            #pragma unroll
            for (int j = 0; j < 4; ++j) {
                int rl = wr * 128 + mf * 16 + rgrp * 4 + j;
                red[rl][wc][0] = m1[mf * 4 + j];
                red[rl][wc][1] = m2[mf * 4 + j];
            }
    }
    __syncthreads();
    if (tid < 256) {
        float p1 = -3.4e38f, p2 = -3.4e38f;
        #pragma unroll
        for (int g = 0; g < 4; ++g) {
            float a1 = red[tid][g][0], a2 = red[tid][g][1];
            float n1 = fmaxf(p1, a1);
            p2 = fmaxf(fminf(p1, a1), fmaxf(p2, a2));
            p1 = n1;
        }
        int row = rowbase + tid;
        fws[PART + ((size_t)row * NCOLT + coltile) * 2 + 0] = p1;
        fws[PART + ((size_t)row * NCOLT + coltile) * 2 + 1] = p2;
    }
}

// ---------------- final: merge partials, arccosh on winners + positive, loss ----------------
__global__ void final_kernel(const char* __restrict__ wsb, const float* __restrict__ curv_log,
                             float* __restrict__ out) {
    const float* fws = (const float*)(wsb + FW_OFF);
    int row = blockIdx.x * 256 + threadIdx.x;
    if (row >= MM) return;
    float curv = __expf(curv_log[0]);
    float rsc = rsqrtf(curv);
    const float* p = fws + PART + (size_t)row * (NCOLT * 2);
    float p1 = -3.4e38f, p2 = -3.4e38f;
    #pragma unroll
    for (int s = 0; s < NCOLT; ++s) {
        float a1 = p[s * 2], a2 = p[s * 2 + 1];
        float n1 = fmaxf(p1, a1);
        p2 = fmaxf(fminf(p1, a1), fmaxf(p2, a2));
        p1 = n1;
    }
    float sa = fws[S_T + row];
    float i1 = sa * p1, i2 = sa * p2;              // negatives: back to Lorentz inner
    float ip = sa * fws[POS + row];                // positive inner (captured in main)
    float cd1 = fmaxf(-curv * i1, 1.0f + EPSF);
    float d1 = __logf(cd1 + sqrtf(cd1 * cd1 - 1.0f)) * rsc;
    float cd2 = fmaxf(-curv * i2, 1.0f + EPSF);
    float d2 = __logf(cd2 + sqrtf(cd2 * cd2 - 1.0f)) * rsc;
    float cdp = fmaxf(-curv * ip, 1.0f + EPSF);
    float dp = __logf(cdp + sqrtf(cdp * cdp - 1.0f)) * rsc;
    float denom = __expf(-dp) + __expf(-d1) + __expf(-d2);
    out[row] = __logf(denom) + dp;
}

extern "C" void kernel_launch(void* const* d_in, const int* in_sizes, int n_in,
                              void* d_out, int out_size, void* d_ws, size_t ws_size,
                              hipStream_t stream) {
    const float* X = (const float*)d_in[0];
    const float* Y = (const float*)d_in[1];
    const int* tgt = (const int*)d_in[2];
    const float* curv_log = (const float*)d_in[3];
    const float* ta_log = (const float*)d_in[4];
    const float* la_log = (const float*)d_in[5];
    char* wsb = (char*)d_ws;
    float* out = (float*)d_out;

    prep_conv_kernel<<<(MM + CC) / 4, 256, 0, stream>>>(X, Y, curv_log, ta_log, la_log, wsb);
    main_kernel<<<NROWT * NCOLT, TPB, 0, stream>>>(tgt, wsb);
    final_kernel<<<MM / 256, 256, 0, stream>>>(wsb, curv_log, out);
}

// Round 14
// 85.474 us; speedup vs baseline: 1.3860x; 1.0379x over previous
//
#include <hip/hip_runtime.h>
#include <hip/hip_bf16.h>
#include <math.h>

#define MM 8192
#define CC 4096
#define DD 768
#define EPSF 1e-8f

#define BM 256
#define BN 256
#define BK 64
#define TPB 512
#define NKT (DD / BK)          // 12 K-tiles
#define NROWT (MM / BM)        // 32
#define NCOLT (CC / BN)        // 16

// ---- ws layout ----
#define XB_OFF 0
#define YB_OFF (MM * DD * 2)
#define FW_OFF (YB_OFF + CC * DD * 2)
#define S_T 0
#define T_T (MM)
#define S_L (2 * MM)
#define T_L (2 * MM + CC)
#define CA_T (2 * MM + 2 * CC)         // t_t / s_t per text row
#define POS  (CA_T + MM)               // Lorentz inner at the positive label (posb_kernel)
#define PART (POS + MM)                // MM * NCOLT * 2 floats (top-2 largest u)

typedef __attribute__((ext_vector_type(8))) short short8;
typedef __attribute__((ext_vector_type(4))) unsigned short u16x4;
typedef __attribute__((ext_vector_type(4))) float f32x4;

__device__ inline unsigned short f2bf(float f) {
    unsigned int u = __float_as_uint(f);
    u += 0x7FFF + ((u >> 16) & 1);   // RNE
    return (unsigned short)(u >> 16);
}

__device__ inline void gll16(const void* g, void* l) {
    __builtin_amdgcn_global_load_lds(
        (const __attribute__((address_space(1))) void*)(uintptr_t)g,
        (__attribute__((address_space(3))) void*)(unsigned)(uintptr_t)l,
        16, 0, 0);
}

#define BAR() do { __builtin_amdgcn_sched_barrier(0); __builtin_amdgcn_s_barrier(); __builtin_amdgcn_sched_barrier(0); } while (0)
#define VM8 asm volatile("s_waitcnt vmcnt(8)" ::: "memory")
#define VM4 asm volatile("s_waitcnt vmcnt(4)" ::: "memory")
#define VM0 asm volatile("s_waitcnt vmcnt(0)" ::: "memory")
#define NOPS ((void)0)

#define DSR(dst, base, off) \
    asm volatile("ds_read_b128 %0, %1 offset:%c2" : "=v"(dst) : "v"(base), "n"(off))

#define MFMA_B(a, b, c) __builtin_amdgcn_mfma_f32_16x16x32_bf16((a), (b), (c), 0, 0, 0)

// ---------------- prep+convert: per-row s,t,ca + bf16 copies ----------------
__global__ void prep_conv_kernel(const float* __restrict__ X, const float* __restrict__ Y,
                                 const float* curv_log, const float* ta_log, const float* la_log,
                                 char* __restrict__ wsb) {
    unsigned short* Xb = (unsigned short*)(wsb + XB_OFF);
    unsigned short* Yb = (unsigned short*)(wsb + YB_OFF);
    float* fws = (float*)(wsb + FW_OFF);
    int wid = threadIdx.x >> 6, lane = threadIdx.x & 63;
    int row = blockIdx.x * 4 + wid;
    float curv = __expf(curv_log[0]);
    const float* src; unsigned short* dst; float alpha; int idx; int is_text;
    if (row < MM) {
        src = X + (size_t)row * DD; dst = Xb + (size_t)row * DD;
        alpha = __expf(ta_log[0]); idx = row; is_text = 1;
    } else {
        int r = row - MM;
        src = Y + (size_t)r * DD; dst = Yb + (size_t)r * DD;
        alpha = __expf(la_log[0]); idx = r; is_text = 0;
    }
    float n2 = 0.f;
    #pragma unroll
    for (int j = 0; j < 3; ++j) {
        float4 v = *(const float4*)(src + lane * 4 + 256 * j);
        n2 += v.x * v.x + v.y * v.y + v.z * v.z + v.w * v.w;
        u16x4 o; o[0] = f2bf(v.x); o[1] = f2bf(v.y); o[2] = f2bf(v.z); o[3] = f2bf(v.w);
        *(u16x4*)(dst + lane * 4 + 256 * j) = o;
    }
    #pragma unroll
    for (int m = 32; m; m >>= 1) n2 += __shfl_xor(n2, m);
    if (lane == 0) {
        float r = sqrtf(curv) * alpha * sqrtf(n2);
        float s = alpha * sinhf(r) / fmaxf(r, EPSF);
        float tt = sqrtf(1.0f / curv + s * s * n2);
        if (is_text) {
            fws[S_T + idx] = s; fws[T_T + idx] = tt; fws[CA_T + idx] = tt / s;
        } else {
            fws[S_L + idx] = s; fws[T_L + idx] = tt;
        }
    }
}

// ---------------- posb: positive Lorentz inner from bf16 copies (half the traffic) --------
__global__ void posb_kernel(const int* __restrict__ tgt, char* __restrict__ wsb) {
    const unsigned* Xb = (const unsigned*)(wsb + XB_OFF);   // rows of 384 dwords (bf16x2)
    const unsigned* Yb = (const unsigned*)(wsb + YB_OFF);
    float* fws = (float*)(wsb + FW_OFF);
    int wid = threadIdx.x >> 6, lane = threadIdx.x & 63;
    int row = blockIdx.x * 4 + wid;
    if (row >= MM) return;
    int t = tgt[row];
    const unsigned* xr = Xb + (size_t)row * (DD / 2);
    const unsigned* yr = Yb + (size_t)t * (DD / 2);
    float dot = 0.f;
    #pragma unroll
    for (int j = 0; j < DD / 2 / 64; ++j) {
        unsigned xv = xr[lane + 64 * j], yv = yr[lane + 64 * j];
        float x0 = __uint_as_float(xv << 16);
        float x1 = __uint_as_float(xv & 0xffff0000u);
        float y0 = __uint_as_float(yv << 16);
        float y1 = __uint_as_float(yv & 0xffff0000u);
        dot += x0 * y0 + x1 * y1;
    }
    #pragma unroll
    for (int m = 32; m; m >>= 1) dot += __shfl_xor(dot, m);
    if (lane == 0)
        fws[POS + row] = fws[S_T + row] * fws[S_L + t] * dot - fws[T_T + row] * fws[T_L + t];
}

// ---------------- main: R6 structure verbatim (best measured) ----------------
__global__ __launch_bounds__(TPB) void main_kernel(
    const int* __restrict__ tgt, char* __restrict__ wsb)
{
    // region rg = (kt&1)*2 + kh; [row 0..255][k-slot 0..3] 64B rows, 16KB.
    // XOR swizzle: byte = row*64 + (slot*16 ^ ((row>>1)&3)<<4) -> 2-way banks on ds_read_b128.
    __shared__ unsigned short Ald[4 * 8192];   // 64KB
    __shared__ unsigned short Bld[4 * 8192];   // 64KB
    __shared__ float red[256][4][2];           // 8KB

    const unsigned short* Xb = (const unsigned short*)(wsb + XB_OFF);
    const unsigned short* Yb = (const unsigned short*)(wsb + YB_OFF);
    float* fws = (float*)(wsb + FW_OFF);

    int tid = threadIdx.x;
    int lane = tid & 63, wid = tid >> 6;
    int wr = wid >> 2, wc = wid & 3;           // 2 row-groups x 4 col-groups
    int l15 = lane & 15, rgrp = lane >> 4;

    // XCD-bijective swizzle: 512 blocks
    int bid = blockIdx.x;
    int pos = bid >> 3;
    int coltile = pos >> 2;                    // 0..15
    int rowpanel = (bid & 7) * 4 + (pos & 3);  // 0..31
    int rowbase = rowpanel * BM;
    int colbase = coltile * BN;

    // staging: LDS slot t (16B, linear) holds row = t>>2, k-octet = (t&3) ^ ((t>>3)&3)
    int ko_src = ((tid & 3) ^ ((tid >> 3) & 3)) * 8;
    const unsigned short* xk = Xb + (size_t)(rowbase + (tid >> 2)) * DD + ko_src;
    const unsigned short* yk = Yb + (size_t)(colbase + (tid >> 2)) * DD + ko_src;
    unsigned short* adst = Ald + tid * 8;
    unsigned short* bdst = Bld + tid * 8;

#define STG_A(OFF, RG) do { gll16(xk + (OFF), adst + (RG) * 8192); \
                            gll16(xk + (size_t)128 * DD + (OFF), adst + (RG) * 8192 + 4096); } while (0)
#define STG_B(OFF, RG) do { gll16(yk + (OFF), bdst + (RG) * 8192); \
                            gll16(yk + (size_t)128 * DD + (OFF), bdst + (RG) * 8192 + 4096); } while (0)

    // fragment read bases with read-side XOR folded in (per-lane constant)
    unsigned a_base = (unsigned)(uintptr_t)(&Ald[0]) + (wr * 128 + l15) * 64
                      + ((rgrp * 16) ^ (((l15 >> 1) & 3) << 4));
    unsigned b_base = (unsigned)(uintptr_t)(&Bld[0]) + (wc * 64 + l15) * 64
                      + ((rgrp * 16) ^ (((l15 >> 1) & 3) << 4));

    f32x4 acc[8][4];
    #pragma unroll
    for (int a = 0; a < 8; ++a)
        #pragma unroll
        for (int b = 0; b < 4; ++b)
            acc[a][b] = (f32x4){0.f, 0.f, 0.f, 0.f};

    short8 af[4], bf[4];

#define MF16(AO) do { \
    acc[(AO)+0][0] = MFMA_B(af[0], bf[0], acc[(AO)+0][0]); \
    acc[(AO)+0][1] = MFMA_B(af[0], bf[1], acc[(AO)+0][1]); \
    acc[(AO)+0][2] = MFMA_B(af[0], bf[2], acc[(AO)+0][2]); \
    acc[(AO)+0][3] = MFMA_B(af[0], bf[3], acc[(AO)+0][3]); \
    acc[(AO)+1][0] = MFMA_B(af[1], bf[0], acc[(AO)+1][0]); \
    acc[(AO)+1][1] = MFMA_B(af[1], bf[1], acc[(AO)+1][1]); \
    acc[(AO)+1][2] = MFMA_B(af[1], bf[2], acc[(AO)+1][2]); \
    acc[(AO)+1][3] = MFMA_B(af[1], bf[3], acc[(AO)+1][3]); \
    acc[(AO)+2][0] = MFMA_B(af[2], bf[0], acc[(AO)+2][0]); \
    acc[(AO)+2][1] = MFMA_B(af[2], bf[1], acc[(AO)+2][1]); \
    acc[(AO)+2][2] = MFMA_B(af[2], bf[2], acc[(AO)+2][2]); \
    acc[(AO)+2][3] = MFMA_B(af[2], bf[3], acc[(AO)+2][3]); \
    acc[(AO)+3][0] = MFMA_B(af[3], bf[0], acc[(AO)+3][0]); \
    acc[(AO)+3][1] = MFMA_B(af[3], bf[1], acc[(AO)+3][1]); \
    acc[(AO)+3][2] = MFMA_B(af[3], bf[2], acc[(AO)+3][2]); \
    acc[(AO)+3][3] = MFMA_B(af[3], bf[3], acc[(AO)+3][3]); \
} while (0)

#define PHASE(RG, MH, AO, STG, W) do { \
    if ((MH) == 0) { \
        DSR(bf[0], b_base, (RG) * 16384 + 0); \
        DSR(bf[1], b_base, (RG) * 16384 + 1024); \
        DSR(bf[2], b_base, (RG) * 16384 + 2048); \
        DSR(bf[3], b_base, (RG) * 16384 + 3072); \
    } \
    DSR(af[0], a_base, (RG) * 16384 + ((MH) * 4 + 0) * 1024); \
    DSR(af[1], a_base, (RG) * 16384 + ((MH) * 4 + 1) * 1024); \
    DSR(af[2], a_base, (RG) * 16384 + ((MH) * 4 + 2) * 1024); \
    DSR(af[3], a_base, (RG) * 16384 + ((MH) * 4 + 3) * 1024); \
    STG; \
    W; \
    BAR(); \
    asm volatile("s_waitcnt lgkmcnt(0)" ::: "memory"); \
    __builtin_amdgcn_sched_barrier(0); \
    __builtin_amdgcn_s_setprio(1); \
    MF16(AO); \
    __builtin_amdgcn_s_setprio(0); \
    BAR(); \
} while (0)

    // prologue: stage rg0(A,B), rg1(A,B), rg2(A,B) = 12 loads; drain rg0
    STG_A(0, 0);  STG_B(0, 0);
    STG_A(32, 1); STG_B(32, 1);
    STG_A(64, 2); STG_B(64, 2);
    VM8;
    BAR();

    // 5 full pairs (kt = 0,2,4,6,8)
    #pragma unroll 1
    for (int kp = 0; kp < 5; ++kp) {
        PHASE(0, 0, 0, STG_A(96, 3),  NOPS);
        PHASE(0, 1, 4, STG_B(96, 3),  VM8);
        PHASE(1, 0, 0, STG_A(128, 0), NOPS);
        PHASE(1, 1, 4, STG_B(128, 0), VM8);
        PHASE(2, 0, 0, STG_A(160, 1), NOPS);
        PHASE(2, 1, 4, STG_B(160, 1), VM8);
        PHASE(3, 0, 0, STG_A(192, 2), NOPS);
        PHASE(3, 1, 4, STG_B(192, 2), VM8);
        xk += 128; yk += 128;
    }
    // tail pair (kt = 10,11)
    PHASE(0, 0, 0, STG_A(96, 3), NOPS);
    PHASE(0, 1, 4, STG_B(96, 3), VM8);
    PHASE(1, 0, 0, NOPS, NOPS);
    PHASE(1, 1, 4, NOPS, VM4);
    PHASE(2, 0, 0, NOPS, NOPS);
    PHASE(2, 1, 4, NOPS, VM0);
    PHASE(3, 0, 0, NOPS, NOPS);
    PHASE(3, 1, 4, NOPS, NOPS);

    // ---- epilogue: per-row top-2 of u = sb*dot - ca*tb (argtop2 == top2 of inner; sa>0) ----
    int colb = colbase + wc * 64 + l15;
    float sbv[4], tbv[4];
    #pragma unroll
    for (int nf = 0; nf < 4; ++nf) { sbv[nf] = fws[S_L + colb + nf * 16]; tbv[nf] = fws[T_L + colb + nf * 16]; }

    float m1[32], m2[32];
    #pragma unroll
    for (int mf = 0; mf < 8; ++mf) {
        int rw = rowbase + wr * 128 + mf * 16 + rgrp * 4;
        #pragma unroll
        for (int j = 0; j < 4; ++j) {
            float ca = fws[CA_T + rw + j];
            int tgj = tgt[rw + j];
            float a = -3.4e38f, b = -3.4e38f;
            #pragma unroll
            for (int nf = 0; nf < 4; ++nf) {
                float u = sbv[nf] * acc[mf][nf][j] - ca * tbv[nf];
                if (colb + nf * 16 == tgj) u = -3.4e38f;
                float n1 = fmaxf(a, u);
                b = fmaxf(b, fminf(a, u));
                a = n1;
            }
            m1[mf * 4 + j] = a; m2[mf * 4 + j] = b;
        }
    }
    #pragma unroll
    for (int mask = 1; mask <= 8; mask <<= 1)
        #pragma unroll
        for (int i = 0; i < 32; ++i) {
            float o1 = __shfl_xor(m1[i], mask);
            float o2 = __shfl_xor(m2[i], mask);
            float n1 = fmaxf(m1[i], o1);
            m2[i] = fmaxf(fminf(m1[i], o1), fmaxf(m2[i], o2));
            m1[i] = n1;
        }
    if (l15 == 0) {
        #pragma unroll
        for (int mf = 0; mf < 8; ++mf)
            #pragma unroll
            for (int j = 0; j < 4; ++j) {
                int rl = wr * 128 + mf * 16 + rgrp * 4 + j;
                red[rl][wc][0] = m1[mf * 4 + j];
                red[rl][wc][1] = m2[mf * 4 + j];
            }
    }
    __syncthreads();
    if (tid < 256) {
        float p1 = -3.4e38f, p2 = -3.4e38f;
        #pragma unroll
        for (int g = 0; g < 4; ++g) {
            float a1 = red[tid][g][0], a2 = red[tid][g][1];
            float n1 = fmaxf(p1, a1);
            p2 = fmaxf(fminf(p1, a1), fmaxf(p2, a2));
            p1 = n1;
        }
        int row = rowbase + tid;
        fws[PART + ((size_t)row * NCOLT + coltile) * 2 + 0] = p1;
        fws[PART + ((size_t)row * NCOLT + coltile) * 2 + 1] = p2;
    }
}

// ---------------- final: merge partials, arccosh on winners + positive, loss ----------------
__global__ void final_kernel(const char* __restrict__ wsb, const float* __restrict__ curv_log,
                             float* __restrict__ out) {
    const float* fws = (const float*)(wsb + FW_OFF);
    int row = blockIdx.x * 256 + threadIdx.x;
    if (row >= MM) return;
    float curv = __expf(curv_log[0]);
    float rsc = rsqrtf(curv);
    const float* p = fws + PART + (size_t)row * (NCOLT * 2);
    float p1 = -3.4e38f, p2 = -3.4e38f;
    #pragma unroll
    for (int s = 0; s < NCOLT; ++s) {
        float a1 = p[s * 2], a2 = p[s * 2 + 1];
        float n1 = fmaxf(p1, a1);
        p2 = fmaxf(fminf(p1, a1), fmaxf(p2, a2));
        p1 = n1;
    }
    float sa = fws[S_T + row];
    float i1 = sa * p1, i2 = sa * p2;              // negatives: back to Lorentz inner
    float ip = fws[POS + row];                     // positive inner (posb_kernel)
    float cd1 = fmaxf(-curv * i1, 1.0f + EPSF);
    float d1 = __logf(cd1 + sqrtf(cd1 * cd1 - 1.0f)) * rsc;
    float cd2 = fmaxf(-curv * i2, 1.0f + EPSF);
    float d2 = __logf(cd2 + sqrtf(cd2 * cd2 - 1.0f)) * rsc;
    float cdp = fmaxf(-curv * ip, 1.0f + EPSF);
    float dp = __logf(cdp + sqrtf(cdp * cdp - 1.0f)) * rsc;
    float denom = __expf(-dp) + __expf(-d1) + __expf(-d2);
    out[row] = __logf(denom) + dp;
}

extern "C" void kernel_launch(void* const* d_in, const int* in_sizes, int n_in,
                              void* d_out, int out_size, void* d_ws, size_t ws_size,
                              hipStream_t stream) {
    const float* X = (const float*)d_in[0];
    const float* Y = (const float*)d_in[1];
    const int* tgt = (const int*)d_in[2];
    const float* curv_log = (const float*)d_in[3];
    const float* ta_log = (const float*)d_in[4];
    const float* la_log = (const float*)d_in[5];
    char* wsb = (char*)d_ws;
    float* out = (float*)d_out;

    prep_conv_kernel<<<(MM + CC) / 4, 256, 0, stream>>>(X, Y, curv_log, ta_log, la_log, wsb);
    posb_kernel<<<MM / 4, 256, 0, stream>>>(tgt, wsb);
    main_kernel<<<NROWT * NCOLT, TPB, 0, stream>>>(tgt, wsb);
    final_kernel<<<MM / 256, 256, 0, stream>>>(wsb, curv_log, out);
}

// Round 16
// 85.214 us; speedup vs baseline: 1.3903x; 1.0031x over previous
//
#include <hip/hip_runtime.h>
#include <hip/hip_bf16.h>
#include <math.h>

#define MM 8192
#define CC 4096
#define DD 768
#define EPSF 1e-8f

#define BM 256
#define BN 256
#define BK 64
#define TPB 512
#define NKT (DD / BK)          // 12 K-tiles
#define NROWT (MM / BM)        // 32
#define NCOLT (CC / BN)        // 16

// ---- ws layout ----
#define XB_OFF 0
#define YB_OFF (MM * DD * 2)
#define FW_OFF (YB_OFF + CC * DD * 2)
#define S_T 0
#define T_T (MM)
#define S_L (2 * MM)
#define T_L (2 * MM + CC)
#define CA_T (2 * MM + 2 * CC)         // t_t / s_t per text row
#define POS  (CA_T + MM)               // Lorentz inner at the positive label (posb_kernel)
#define PART (POS + MM)                // MM * NCOLT * 2 floats (top-2 largest u)

typedef __attribute__((ext_vector_type(8))) short short8;
typedef __attribute__((ext_vector_type(4))) unsigned short u16x4;
typedef __attribute__((ext_vector_type(4))) float f32x4;

__device__ inline unsigned short f2bf(float f) {
    unsigned int u = __float_as_uint(f);
    u += 0x7FFF + ((u >> 16) & 1);   // RNE
    return (unsigned short)(u >> 16);
}

__device__ inline void gll16(const void* g, void* l) {
    __builtin_amdgcn_global_load_lds(
        (const __attribute__((address_space(1))) void*)(uintptr_t)g,
        (__attribute__((address_space(3))) void*)(unsigned)(uintptr_t)l,
        16, 0, 0);
}

#define BAR() do { __builtin_amdgcn_sched_barrier(0); __builtin_amdgcn_s_barrier(); __builtin_amdgcn_sched_barrier(0); } while (0)
#define VM8 asm volatile("s_waitcnt vmcnt(8)" ::: "memory")
#define VM4 asm volatile("s_waitcnt vmcnt(4)" ::: "memory")
#define VM0 asm volatile("s_waitcnt vmcnt(0)" ::: "memory")
#define NOPS ((void)0)

#define DSR(dst, base, off) \
    asm volatile("ds_read_b128 %0, %1 offset:%c2" : "=v"(dst) : "v"(base), "n"(off))

#define MFMA_B(a, b, c) __builtin_amdgcn_mfma_f32_16x16x32_bf16((a), (b), (c), 0, 0, 0)

// ---------------- prep+convert: per-row s,t,ca + bf16 copies ----------------
__global__ void prep_conv_kernel(const float* __restrict__ X, const float* __restrict__ Y,
                                 const float* curv_log, const float* ta_log, const float* la_log,
                                 char* __restrict__ wsb) {
    unsigned short* Xb = (unsigned short*)(wsb + XB_OFF);
    unsigned short* Yb = (unsigned short*)(wsb + YB_OFF);
    float* fws = (float*)(wsb + FW_OFF);
    int wid = threadIdx.x >> 6, lane = threadIdx.x & 63;
    int row = blockIdx.x * 4 + wid;
    float curv = __expf(curv_log[0]);
    const float* src; unsigned short* dst; float alpha; int idx; int is_text;
    if (row < MM) {
        src = X + (size_t)row * DD; dst = Xb + (size_t)row * DD;
        alpha = __expf(ta_log[0]); idx = row; is_text = 1;
    } else {
        int r = row - MM;
        src = Y + (size_t)r * DD; dst = Yb + (size_t)r * DD;
        alpha = __expf(la_log[0]); idx = r; is_text = 0;
    }
    float n2 = 0.f;
    #pragma unroll
    for (int j = 0; j < 3; ++j) {
        float4 v = *(const float4*)(src + lane * 4 + 256 * j);
        n2 += v.x * v.x + v.y * v.y + v.z * v.z + v.w * v.w;
        u16x4 o; o[0] = f2bf(v.x); o[1] = f2bf(v.y); o[2] = f2bf(v.z); o[3] = f2bf(v.w);
        *(u16x4*)(dst + lane * 4 + 256 * j) = o;
    }
    #pragma unroll
    for (int m = 32; m; m >>= 1) n2 += __shfl_xor(n2, m);
    if (lane == 0) {
        float r = sqrtf(curv) * alpha * sqrtf(n2);
        float s = alpha * sinhf(r) / fmaxf(r, EPSF);
        float tt = sqrtf(1.0f / curv + s * s * n2);
        if (is_text) {
            fws[S_T + idx] = s; fws[T_T + idx] = tt; fws[CA_T + idx] = tt / s;
        } else {
            fws[S_L + idx] = s; fws[T_L + idx] = tt;
        }
    }
}

// ---------------- posb: positive Lorentz inner from bf16 copies (half the traffic) --------
__global__ void posb_kernel(const int* __restrict__ tgt, char* __restrict__ wsb) {
    const unsigned* Xb = (const unsigned*)(wsb + XB_OFF);   // rows of 384 dwords (bf16x2)
    const unsigned* Yb = (const unsigned*)(wsb + YB_OFF);
    float* fws = (float*)(wsb + FW_OFF);
    int wid = threadIdx.x >> 6, lane = threadIdx.x & 63;
    int row = blockIdx.x * 4 + wid;
    if (row >= MM) return;
    int t = tgt[row];
    const unsigned* xr = Xb + (size_t)row * (DD / 2);
    const unsigned* yr = Yb + (size_t)t * (DD / 2);
    float dot = 0.f;
    #pragma unroll
    for (int j = 0; j < DD / 2 / 64; ++j) {
        unsigned xv = xr[lane + 64 * j], yv = yr[lane + 64 * j];
        float x0 = __uint_as_float(xv << 16);
        float x1 = __uint_as_float(xv & 0xffff0000u);
        float y0 = __uint_as_float(yv << 16);
        float y1 = __uint_as_float(yv & 0xffff0000u);
        dot += x0 * y0 + x1 * y1;
    }
    #pragma unroll
    for (int m = 32; m; m >>= 1) dot += __shfl_xor(dot, m);
    if (lane == 0)
        fws[POS + row] = fws[S_T + row] * fws[S_L + t] * dot - fws[T_T + row] * fws[T_L + t];
}

// ---------------- main: R6 structure verbatim (best measured) ----------------
__global__ __launch_bounds__(TPB) void main_kernel(
    const int* __restrict__ tgt, char* __restrict__ wsb)
{
    // region rg = (kt&1)*2 + kh; [row 0..255][k-slot 0..3] 64B rows, 16KB.
    // XOR swizzle: byte = row*64 + (slot*16 ^ ((row>>1)&3)<<4) -> 2-way banks on ds_read_b128.
    __shared__ unsigned short Ald[4 * 8192];   // 64KB
    __shared__ unsigned short Bld[4 * 8192];   // 64KB
    __shared__ float red[256][4][2];           // 8KB

    const unsigned short* Xb = (const unsigned short*)(wsb + XB_OFF);
    const unsigned short* Yb = (const unsigned short*)(wsb + YB_OFF);
    float* fws = (float*)(wsb + FW_OFF);

    int tid = threadIdx.x;
    int lane = tid & 63, wid = tid >> 6;
    int wr = wid >> 2, wc = wid & 3;           // 2 row-groups x 4 col-groups
    int l15 = lane & 15, rgrp = lane >> 4;

    // XCD-bijective swizzle: 512 blocks
    int bid = blockIdx.x;
    int pos = bid >> 3;
    int coltile = pos >> 2;                    // 0..15
    int rowpanel = (bid & 7) * 4 + (pos & 3);  // 0..31
    int rowbase = rowpanel * BM;
    int colbase = coltile * BN;

    // staging: LDS slot t (16B, linear) holds row = t>>2, k-octet = (t&3) ^ ((t>>3)&3)
    int ko_src = ((tid & 3) ^ ((tid >> 3) & 3)) * 8;
    const unsigned short* xk = Xb + (size_t)(rowbase + (tid >> 2)) * DD + ko_src;
    const unsigned short* yk = Yb + (size_t)(colbase + (tid >> 2)) * DD + ko_src;
    unsigned short* adst = Ald + tid * 8;
    unsigned short* bdst = Bld + tid * 8;

#define STG_A(OFF, RG) do { gll16(xk + (OFF), adst + (RG) * 8192); \
                            gll16(xk + (size_t)128 * DD + (OFF), adst + (RG) * 8192 + 4096); } while (0)
#define STG_B(OFF, RG) do { gll16(yk + (OFF), bdst + (RG) * 8192); \
                            gll16(yk + (size_t)128 * DD + (OFF), bdst + (RG) * 8192 + 4096); } while (0)

    // fragment read bases with read-side XOR folded in (per-lane constant)
    unsigned a_base = (unsigned)(uintptr_t)(&Ald[0]) + (wr * 128 + l15) * 64
                      + ((rgrp * 16) ^ (((l15 >> 1) & 3) << 4));
    unsigned b_base = (unsigned)(uintptr_t)(&Bld[0]) + (wc * 64 + l15) * 64
                      + ((rgrp * 16) ^ (((l15 >> 1) & 3) << 4));

    f32x4 acc[8][4];
    #pragma unroll
    for (int a = 0; a < 8; ++a)
        #pragma unroll
        for (int b = 0; b < 4; ++b)
            acc[a][b] = (f32x4){0.f, 0.f, 0.f, 0.f};

    short8 af[4], bf[4];

#define MF16(AO) do { \
    acc[(AO)+0][0] = MFMA_B(af[0], bf[0], acc[(AO)+0][0]); \
    acc[(AO)+0][1] = MFMA_B(af[0], bf[1], acc[(AO)+0][1]); \
    acc[(AO)+0][2] = MFMA_B(af[0], bf[2], acc[(AO)+0][2]); \
    acc[(AO)+0][3] = MFMA_B(af[0], bf[3], acc[(AO)+0][3]); \
    acc[(AO)+1][0] = MFMA_B(af[1], bf[0], acc[(AO)+1][0]); \
    acc[(AO)+1][1] = MFMA_B(af[1], bf[1], acc[(AO)+1][1]); \
    acc[(AO)+1][2] = MFMA_B(af[1], bf[2], acc[(AO)+1][2]); \
    acc[(AO)+1][3] = MFMA_B(af[1], bf[3], acc[(AO)+1][3]); \
    acc[(AO)+2][0] = MFMA_B(af[2], bf[0], acc[(AO)+2][0]); \
    acc[(AO)+2][1] = MFMA_B(af[2], bf[1], acc[(AO)+2][1]); \
    acc[(AO)+2][2] = MFMA_B(af[2], bf[2], acc[(AO)+2][2]); \
    acc[(AO)+2][3] = MFMA_B(af[2], bf[3], acc[(AO)+2][3]); \
    acc[(AO)+3][0] = MFMA_B(af[3], bf[0], acc[(AO)+3][0]); \
    acc[(AO)+3][1] = MFMA_B(af[3], bf[1], acc[(AO)+3][1]); \
    acc[(AO)+3][2] = MFMA_B(af[3], bf[2], acc[(AO)+3][2]); \
    acc[(AO)+3][3] = MFMA_B(af[3], bf[3], acc[(AO)+3][3]); \
} while (0)

#define PHASE(RG, MH, AO, STG, W) do { \
    if ((MH) == 0) { \
        DSR(bf[0], b_base, (RG) * 16384 + 0); \
        DSR(bf[1], b_base, (RG) * 16384 + 1024); \
        DSR(bf[2], b_base, (RG) * 16384 + 2048); \
        DSR(bf[3], b_base, (RG) * 16384 + 3072); \
    } \
    DSR(af[0], a_base, (RG) * 16384 + ((MH) * 4 + 0) * 1024); \
    DSR(af[1], a_base, (RG) * 16384 + ((MH) * 4 + 1) * 1024); \
    DSR(af[2], a_base, (RG) * 16384 + ((MH) * 4 + 2) * 1024); \
    DSR(af[3], a_base, (RG) * 16384 + ((MH) * 4 + 3) * 1024); \
    STG; \
    W; \
    BAR(); \
    asm volatile("s_waitcnt lgkmcnt(0)" ::: "memory"); \
    __builtin_amdgcn_sched_barrier(0); \
    __builtin_amdgcn_s_setprio(1); \
    MF16(AO); \
    __builtin_amdgcn_s_setprio(0); \
    BAR(); \
} while (0)

    // prologue: stage rg0(A,B), rg1(A,B), rg2(A,B) = 12 loads; drain rg0
    STG_A(0, 0);  STG_B(0, 0);
    STG_A(32, 1); STG_B(32, 1);
    STG_A(64, 2); STG_B(64, 2);
    VM8;
    BAR();

    // 5 full pairs (kt = 0,2,4,6,8)
    #pragma unroll 1
    for (int kp = 0; kp < 5; ++kp) {
        PHASE(0, 0, 0, STG_A(96, 3),  NOPS);
        PHASE(0, 1, 4, STG_B(96, 3),  VM8);
        PHASE(1, 0, 0, STG_A(128, 0), NOPS);
        PHASE(1, 1, 4, STG_B(128, 0), VM8);
        PHASE(2, 0, 0, STG_A(160, 1), NOPS);
        PHASE(2, 1, 4, STG_B(160, 1), VM8);
        PHASE(3, 0, 0, STG_A(192, 2), NOPS);
        PHASE(3, 1, 4, STG_B(192, 2), VM8);
        xk += 128; yk += 128;
    }
    // tail pair (kt = 10,11)
    PHASE(0, 0, 0, STG_A(96, 3), NOPS);
    PHASE(0, 1, 4, STG_B(96, 3), VM8);
    PHASE(1, 0, 0, NOPS, NOPS);
    PHASE(1, 1, 4, NOPS, VM4);
    PHASE(2, 0, 0, NOPS, NOPS);
    PHASE(2, 1, 4, NOPS, VM0);
    PHASE(3, 0, 0, NOPS, NOPS);
    PHASE(3, 1, 4, NOPS, NOPS);

    // ---- epilogue: per-row top-2 of u = sb*dot - ca*tb (argtop2 == top2 of inner; sa>0) ----
    int colb = colbase + wc * 64 + l15;
    float sbv[4], tbv[4];
    #pragma unroll
    for (int nf = 0; nf < 4; ++nf) { sbv[nf] = fws[S_L + colb + nf * 16]; tbv[nf] = fws[T_L + colb + nf * 16]; }

    float m1[32], m2[32];
    #pragma unroll
    for (int mf = 0; mf < 8; ++mf) {
        int rw = rowbase + wr * 128 + mf * 16 + rgrp * 4;
        #pragma unroll
        for (int j = 0; j < 4; ++j) {
            float ca = fws[CA_T + rw + j];
            int tgj = tgt[rw + j];
            float a = -3.4e38f, b = -3.4e38f;
            #pragma unroll
            for (int nf = 0; nf < 4; ++nf) {
                float u = sbv[nf] * acc[mf][nf][j] - ca * tbv[nf];
                if (colb + nf * 16 == tgj) u = -3.4e38f;
                float n1 = fmaxf(a, u);
                b = fmaxf(b, fminf(a, u));
                a = n1;
            }
            m1[mf * 4 + j] = a; m2[mf * 4 + j] = b;
        }
    }
    #pragma unroll
    for (int mask = 1; mask <= 8; mask <<= 1)
        #pragma unroll
        for (int i = 0; i < 32; ++i) {
            float o1 = __shfl_xor(m1[i], mask);
            float o2 = __shfl_xor(m2[i], mask);
            float n1 = fmaxf(m1[i], o1);
            m2[i] = fmaxf(fminf(m1[i], o1), fmaxf(m2[i], o2));
            m1[i] = n1;
        }
    if (l15 == 0) {
        #pragma unroll
        for (int mf = 0; mf < 8; ++mf)
            #pragma unroll
            for (int j = 0; j < 4; ++j) {
                int rl = wr * 128 + mf * 16 + rgrp * 4 + j;
                red[rl][wc][0] = m1[mf * 4 + j];
                red[rl][wc][1] = m2[mf * 4 + j];
            }
    }
    __syncthreads();
    if (tid < 256) {
        float p1 = -3.4e38f, p2 = -3.4e38f;
        #pragma unroll
        for (int g = 0; g < 4; ++g) {
            float a1 = red[tid][g][0], a2 = red[tid][g][1];
            float n1 = fmaxf(p1, a1);
            p2 = fmaxf(fminf(p1, a1), fmaxf(p2, a2));
            p1 = n1;
        }
        int row = rowbase + tid;
        fws[PART + ((size_t)row * NCOLT + coltile) * 2 + 0] = p1;
        fws[PART + ((size_t)row * NCOLT + coltile) * 2 + 1] = p2;
    }
}

// ---------------- final: merge partials, arccosh on winners + positive, loss ----------------
__global__ void final_kernel(const char* __restrict__ wsb, const float* __restrict__ curv_log,
                             float* __restrict__ out) {
    const float* fws = (const float*)(wsb + FW_OFF);
    int row = blockIdx.x * 256 + threadIdx.x;
    if (row >= MM) return;
    float curv = __expf(curv_log[0]);
    float rsc = rsqrtf(curv);
    const float* p = fws + PART + (size_t)row * (NCOLT * 2);
    float p1 = -3.4e38f, p2 = -3.4e38f;
    #pragma unroll
    for (int s = 0; s < NCOLT; ++s) {
        float a1 = p[s * 2], a2 = p[s * 2 + 1];
        float n1 = fmaxf(p1, a1);
        p2 = fmaxf(fminf(p1, a1), fmaxf(p2, a2));
        p1 = n1;
    }
    float sa = fws[S_T + row];
    float i1 = sa * p1, i2 = sa * p2;              // negatives: back to Lorentz inner
    float ip = fws[POS + row];                     // positive inner (posb_kernel)
    float cd1 = fmaxf(-curv * i1, 1.0f + EPSF);
    float d1 = __logf(cd1 + sqrtf(cd1 * cd1 - 1.0f)) * rsc;
    float cd2 = fmaxf(-curv * i2, 1.0f + EPSF);
    float d2 = __logf(cd2 + sqrtf(cd2 * cd2 - 1.0f)) * rsc;
    float cdp = fmaxf(-curv * ip, 1.0f + EPSF);
    float dp = __logf(cdp + sqrtf(cdp * cdp - 1.0f)) * rsc;
    float denom = __expf(-dp) + __expf(-d1) + __expf(-d2);
    out[row] = __logf(denom) + dp;
}

extern "C" void kernel_launch(void* const* d_in, const int* in_sizes, int n_in,
                              void* d_out, int out_size, void* d_ws, size_t ws_size,
                              hipStream_t stream) {
    const float* X = (const float*)d_in[0];
    const float* Y = (const float*)d_in[1];
    const int* tgt = (const int*)d_in[2];
    const float* curv_log = (const float*)d_in[3];
    const float* ta_log = (const float*)d_in[4];
    const float* la_log = (const float*)d_in[5];
    char* wsb = (char*)d_ws;
    float* out = (float*)d_out;

    prep_conv_kernel<<<(MM + CC) / 4, 256, 0, stream>>>(X, Y, curv_log, ta_log, la_log, wsb);
    posb_kernel<<<MM / 4, 256, 0, stream>>>(tgt, wsb);
    main_kernel<<<NROWT * NCOLT, TPB, 0, stream>>>(tgt, wsb);
    final_kernel<<<MM / 256, 256, 0, stream>>>(wsb, curv_log, out);
}